// Round 1
// baseline (676.419 us; speedup 1.0000x reference)
//
#include <hip/hip_runtime.h>
#include <hip/hip_bf16.h>
#include <math.h>

#define N_NODES 50000
#define N_EDGES 800000
#define ET (N_EDGES + N_NODES)   // with self loops = 850000
#define F0 128
#define H1 8
#define C1 32
#define D1 (H1*C1)               // 256
#define C2 32
#define C3 64

__device__ __forceinline__ float lrelu(float x) { return x >= 0.f ? x : 0.2f * x; }
__device__ __forceinline__ float eluf(float x)  { return x > 0.f ? x : (expf(x) - 1.f); }

// ---------------- CSR build ----------------

__global__ void hist_kernel(const int* __restrict__ dstArr, int* __restrict__ deg) {
    int e = blockIdx.x * 256 + threadIdx.x;
    if (e >= ET) return;
    int d = (e < N_EDGES) ? dstArr[e] : (e - N_EDGES);
    atomicAdd(&deg[d], 1);
}

__global__ __launch_bounds__(1024) void scan_kernel(const int* __restrict__ deg,
                                                    int* __restrict__ off,
                                                    int* __restrict__ cur, int n) {
    __shared__ int sdata[1024];
    __shared__ int s_carry;
    int t = threadIdx.x;
    if (t == 0) s_carry = 0;
    __syncthreads();
    const int CH = 8;
    for (int base = 0; base < n; base += 1024 * CH) {
        int idx0 = base + t * CH;
        int v[CH];
        int sum = 0;
#pragma unroll
        for (int u = 0; u < CH; ++u) {
            int ix = idx0 + u;
            int x = (ix < n) ? deg[ix] : 0;
            v[u] = sum;
            sum += x;
        }
        sdata[t] = sum;
        __syncthreads();
        for (int o = 1; o < 1024; o <<= 1) {
            int x = (t >= o) ? sdata[t - o] : 0;
            __syncthreads();
            sdata[t] += x;
            __syncthreads();
        }
        int excl = sdata[t] - sum + s_carry;   // read s_carry before it is updated
#pragma unroll
        for (int u = 0; u < CH; ++u) {
            int ix = idx0 + u;
            if (ix < n) { int val = excl + v[u]; off[ix] = val; cur[ix] = val; }
        }
        __syncthreads();
        if (t == 1023) s_carry = s_carry + sdata[1023];
        __syncthreads();
    }
    if (t == 0) off[n] = s_carry;
}

__global__ void scatter_kernel(const int* __restrict__ srcArr, const int* __restrict__ dstArr,
                               int* __restrict__ cur, int* __restrict__ csr) {
    int e = blockIdx.x * 256 + threadIdx.x;
    if (e >= ET) return;
    int s, d;
    if (e < N_EDGES) { s = srcArr[e]; d = dstArr[e]; } else { s = d = e - N_EDGES; }
    int pos = atomicAdd(&cur[d], 1);
    csr[pos] = s;
}

// ---------------- GEMM: C[M,N] = A[M,K] @ B[K,N], f32, K % 16 == 0 ----------------

#define GBM 64
#define GBN 64
#define GBK 16

__global__ __launch_bounds__(256) void gemm_kernel(const float* __restrict__ A,
                                                   const float* __restrict__ B,
                                                   float* __restrict__ C,
                                                   int M, int N, int K) {
    __shared__ float As[GBK][GBM];
    __shared__ float Bs[GBK][GBN];
    int tid = threadIdx.x;
    int bm = blockIdx.y * GBM;
    int bn = blockIdx.x * GBN;
    int tx = tid & 15;   // col group (4 cols)
    int ty = tid >> 4;   // row group (4 rows)
    float acc[4][4] = {};

    for (int k0 = 0; k0 < K; k0 += GBK) {
        {
            int kk = tid & 15;
            int r0 = tid >> 4;
            for (int rr = r0; rr < GBM; rr += 16) {
                int gr = bm + rr;
                As[kk][rr] = (gr < M) ? A[(size_t)gr * K + k0 + kk] : 0.f;
            }
        }
        {
            int j = tid & 63;
            int k1 = tid >> 6;
            for (int k2 = k1; k2 < GBK; k2 += 4) {
                int gj = bn + j;
                Bs[k2][j] = (gj < N) ? B[(size_t)(k0 + k2) * N + gj] : 0.f;
            }
        }
        __syncthreads();
#pragma unroll
        for (int kk = 0; kk < GBK; ++kk) {
            float4 av = *(const float4*)&As[kk][ty * 4];
            float4 bv = *(const float4*)&Bs[kk][tx * 4];
            float a[4] = {av.x, av.y, av.z, av.w};
            float b[4] = {bv.x, bv.y, bv.z, bv.w};
#pragma unroll
            for (int i = 0; i < 4; ++i)
#pragma unroll
                for (int j = 0; j < 4; ++j)
                    acc[i][j] += a[i] * b[j];
        }
        __syncthreads();
    }
#pragma unroll
    for (int i = 0; i < 4; ++i) {
        int gr = bm + ty * 4 + i;
        if (gr >= M) continue;
#pragma unroll
        for (int j = 0; j < 4; ++j) {
            int gc = bn + tx * 4 + j;
            if (gc < N) C[(size_t)gr * N + gc] = acc[i][j];
        }
    }
}

// ---------------- per-node attention coefficients ----------------
// h: [n, H*C]; a_src/a_dst: [H, C]; out as/ad: [n*H]

__global__ void alpha_kernel(const float* __restrict__ h, const float* __restrict__ a_src,
                             const float* __restrict__ a_dst, float* __restrict__ as,
                             float* __restrict__ ad, int n, int H, int C) {
    int t = blockIdx.x * 256 + threadIdx.x;
    if (t >= n * H) return;
    int hh = t % H;
    const float* hp  = h + (size_t)t * C;
    const float* asp = a_src + hh * C;
    const float* adp = a_dst + hh * C;
    float s1 = 0.f, s2 = 0.f;
    for (int c = 0; c < C; c += 4) {
        float4 hv = *(const float4*)(hp + c);
        float4 sv = *(const float4*)(asp + c);
        float4 dv = *(const float4*)(adp + c);
        s1 += hv.x * sv.x + hv.y * sv.y + hv.z * sv.z + hv.w * sv.w;
        s2 += hv.x * dv.x + hv.y * dv.y + hv.z * dv.z + hv.w * dv.w;
    }
    as[t] = s1;
    ad[t] = s2;
}

// ---------------- layer 1 aggregation: H=8, C=32, wave per node ----------------

__global__ __launch_bounds__(256) void agg1_kernel(const int* __restrict__ off, const int* __restrict__ csr,
                                                   const float* __restrict__ h, const float* __restrict__ as,
                                                   const float* __restrict__ ad, const float* __restrict__ bias,
                                                   float* __restrict__ out) {
    int node = blockIdx.x * 4 + (threadIdx.x >> 6);
    if (node >= N_NODES) return;
    int lane = threadIdx.x & 63;
    int hh = lane >> 3;
    int j  = lane & 7;
    int s0 = off[node];
    int deg = off[node + 1] - s0;
    float adv = ad[node * H1 + hh];
    int myidx = (lane < deg) ? csr[s0 + lane] : 0;

    float m = -INFINITY;
    for (int i = j; i < deg; i += 8) {
        int s = (i < 64) ? __shfl(myidx, i) : csr[s0 + i];
        float e = lrelu(as[s * H1 + hh] + adv);
        m = fmaxf(m, e);
    }
    m = fmaxf(m, __shfl_xor(m, 1));
    m = fmaxf(m, __shfl_xor(m, 2));
    m = fmaxf(m, __shfl_xor(m, 4));

    float dsum = 0.f;
    for (int i = j; i < deg; i += 8) {
        int s = (i < 64) ? __shfl(myidx, i) : csr[s0 + i];
        float e = lrelu(as[s * H1 + hh] + adv);
        dsum += __expf(e - m);
    }
    dsum += __shfl_xor(dsum, 1);
    dsum += __shfl_xor(dsum, 2);
    dsum += __shfl_xor(dsum, 4);

    float4 acc = make_float4(0.f, 0.f, 0.f, 0.f);
    for (int i = 0; i < deg; ++i) {
        int s = (i < 64) ? __shfl(myidx, i) : csr[s0 + i];
        float e = lrelu(as[s * H1 + hh] + adv);
        float w = __expf(e - m);
        float4 hv = *(const float4*)(h + (size_t)s * D1 + hh * C1 + j * 4);
        acc.x += w * hv.x; acc.y += w * hv.y; acc.z += w * hv.z; acc.w += w * hv.w;
    }
    float inv = 1.f / (dsum + 1e-16f);
    int ob = node * D1 + hh * C1 + j * 4;
    const float* bp = bias + hh * C1 + j * 4;
    float4 r;
    r.x = eluf(acc.x * inv + bp[0]);
    r.y = eluf(acc.y * inv + bp[1]);
    r.z = eluf(acc.z * inv + bp[2]);
    r.w = eluf(acc.w * inv + bp[3]);
    *(float4*)(out + ob) = r;
}

// ---------------- layer 2 aggregation: H=1, C=32, wave per node ----------------

__global__ __launch_bounds__(256) void agg32_kernel(const int* __restrict__ off, const int* __restrict__ csr,
                                                    const float* __restrict__ h, const float* __restrict__ as,
                                                    const float* __restrict__ ad, const float* __restrict__ bias,
                                                    float* __restrict__ out) {
    int node = blockIdx.x * 4 + (threadIdx.x >> 6);
    if (node >= N_NODES) return;
    int lane = threadIdx.x & 63;
    int s0 = off[node];
    int deg = off[node + 1] - s0;
    float adv = ad[node];
    int myidx = (lane < deg) ? csr[s0 + lane] : 0;

    float m = -INFINITY;
    for (int i = lane; i < deg; i += 64) {
        int s = (i < 64) ? __shfl(myidx, i) : csr[s0 + i];
        m = fmaxf(m, lrelu(as[s] + adv));
    }
#pragma unroll
    for (int o = 1; o < 64; o <<= 1) m = fmaxf(m, __shfl_xor(m, o));

    float dsum = 0.f;
    for (int i = lane; i < deg; i += 64) {
        int s = (i < 64) ? __shfl(myidx, i) : csr[s0 + i];
        dsum += __expf(lrelu(as[s] + adv) - m);
    }
#pragma unroll
    for (int o = 1; o < 64; o <<= 1) dsum += __shfl_xor(dsum, o);

    int c = lane & 31;
    int half = lane >> 5;
    float acc = 0.f;
    for (int i = half; i < deg; i += 2) {
        int s = (i < 64) ? __shfl(myidx, i) : csr[s0 + i];
        float w = __expf(lrelu(as[s] + adv) - m);
        acc += w * h[(size_t)s * C2 + c];
    }
    acc += __shfl_xor(acc, 32);
    if (half == 0) {
        float r = acc / (dsum + 1e-16f) + bias[c];
        out[(size_t)node * C2 + c] = eluf(r);
    }
}

// ---------------- layer 3 aggregation: H=1, C=64, wave per node, no ELU ----------------

__global__ __launch_bounds__(256) void agg64_kernel(const int* __restrict__ off, const int* __restrict__ csr,
                                                    const float* __restrict__ h, const float* __restrict__ as,
                                                    const float* __restrict__ ad, const float* __restrict__ bias,
                                                    float* __restrict__ out) {
    int node = blockIdx.x * 4 + (threadIdx.x >> 6);
    if (node >= N_NODES) return;
    int lane = threadIdx.x & 63;
    int s0 = off[node];
    int deg = off[node + 1] - s0;
    float adv = ad[node];
    int myidx = (lane < deg) ? csr[s0 + lane] : 0;

    float m = -INFINITY;
    for (int i = lane; i < deg; i += 64) {
        int s = (i < 64) ? __shfl(myidx, i) : csr[s0 + i];
        m = fmaxf(m, lrelu(as[s] + adv));
    }
#pragma unroll
    for (int o = 1; o < 64; o <<= 1) m = fmaxf(m, __shfl_xor(m, o));

    float dsum = 0.f;
    for (int i = lane; i < deg; i += 64) {
        int s = (i < 64) ? __shfl(myidx, i) : csr[s0 + i];
        dsum += __expf(lrelu(as[s] + adv) - m);
    }
#pragma unroll
    for (int o = 1; o < 64; o <<= 1) dsum += __shfl_xor(dsum, o);

    float acc = 0.f;
    for (int i = 0; i < deg; ++i) {
        int s = (i < 64) ? __shfl(myidx, i) : csr[s0 + i];
        float w = __expf(lrelu(as[s] + adv) - m);
        acc += w * h[(size_t)s * C3 + lane];
    }
    out[(size_t)node * C3 + lane] = acc / (dsum + 1e-16f) + bias[lane];
}

// ---------------- launch ----------------

extern "C" void kernel_launch(void* const* d_in, const int* in_sizes, int n_in,
                              void* d_out, int out_size, void* d_ws, size_t ws_size,
                              hipStream_t stream) {
    const float* x   = (const float*)d_in[0];
    const int*   ei  = (const int*)d_in[1];     // [2, E]: row0 src, row1 dst
    const float* W1  = (const float*)d_in[2];
    const float* aS1 = (const float*)d_in[3];
    const float* aD1 = (const float*)d_in[4];
    const float* b1  = (const float*)d_in[5];
    const float* W2  = (const float*)d_in[6];
    const float* aS2 = (const float*)d_in[7];
    const float* aD2 = (const float*)d_in[8];
    const float* b2  = (const float*)d_in[9];
    const float* W3  = (const float*)d_in[10];
    const float* aS3 = (const float*)d_in[11];
    const float* aD3 = (const float*)d_in[12];
    const float* b3  = (const float*)d_in[13];
    float* out = (float*)d_out;

    // workspace layout
    char* p = (char*)d_ws;
    auto alloc = [&](size_t bytes) -> void* {
        void* r = (void*)p;
        p += (bytes + 255) & ~(size_t)255;
        return r;
    };
    float* bufA = (float*)alloc((size_t)N_NODES * D1 * 4);   // h1 / h2 / h3
    float* bufB = (float*)alloc((size_t)N_NODES * D1 * 4);   // x2 / x3
    int*   deg  = (int*)alloc((size_t)N_NODES * 4);
    int*   off  = (int*)alloc((size_t)(N_NODES + 1) * 4);
    int*   cur  = (int*)alloc((size_t)N_NODES * 4);
    int*   csr  = (int*)alloc((size_t)ET * 4);
    float* asb  = (float*)alloc((size_t)N_NODES * H1 * 4);
    float* adb  = (float*)alloc((size_t)N_NODES * H1 * 4);

    const int* srcArr = ei;
    const int* dstArr = ei + N_EDGES;

    // --- CSR build ---
    hipMemsetAsync(deg, 0, (size_t)N_NODES * 4, stream);
    int eb = (ET + 255) / 256;
    hist_kernel<<<eb, 256, 0, stream>>>(dstArr, deg);
    scan_kernel<<<1, 1024, 0, stream>>>(deg, off, cur, N_NODES);
    scatter_kernel<<<eb, 256, 0, stream>>>(srcArr, dstArr, cur, csr);

    int mtiles = (N_NODES + GBM - 1) / GBM;   // 782
    int nb4 = (N_NODES + 3) / 4;              // 12500

    // --- layer 1 ---
    gemm_kernel<<<dim3((D1 + GBN - 1) / GBN, mtiles), 256, 0, stream>>>(x, W1, bufA, N_NODES, D1, F0);
    alpha_kernel<<<(N_NODES * H1 + 255) / 256, 256, 0, stream>>>(bufA, aS1, aD1, asb, adb, N_NODES, H1, C1);
    agg1_kernel<<<nb4, 256, 0, stream>>>(off, csr, bufA, asb, adb, b1, bufB);

    // --- layer 2 ---
    gemm_kernel<<<dim3((C2 + GBN - 1) / GBN, mtiles), 256, 0, stream>>>(bufB, W2, bufA, N_NODES, C2, D1);
    alpha_kernel<<<(N_NODES + 255) / 256, 256, 0, stream>>>(bufA, aS2, aD2, asb, adb, N_NODES, 1, C2);
    agg32_kernel<<<nb4, 256, 0, stream>>>(off, csr, bufA, asb, adb, b2, bufB);

    // --- layer 3 ---
    gemm_kernel<<<dim3((C3 + GBN - 1) / GBN, mtiles), 256, 0, stream>>>(bufB, W3, bufA, N_NODES, C3, C2);
    alpha_kernel<<<(N_NODES + 255) / 256, 256, 0, stream>>>(bufA, aS3, aD3, asb, adb, N_NODES, 1, C3);
    agg64_kernel<<<nb4, 256, 0, stream>>>(off, csr, bufA, asb, adb, b3, out);
}

// Round 2
// 645.030 us; speedup vs baseline: 1.0487x; 1.0487x over previous
//
#include <hip/hip_runtime.h>
#include <hip/hip_bf16.h>
#include <math.h>

#define N_NODES 50000
#define N_EDGES 800000
#define ET (N_EDGES + N_NODES)   // with self loops = 850000
#define F0 128
#define H1 8
#define C1 32
#define D1 (H1*C1)               // 256
#define C2 32
#define C3 64

__device__ __forceinline__ float lrelu(float x) { return x >= 0.f ? x : 0.2f * x; }
__device__ __forceinline__ float eluf(float x)  { return x > 0.f ? x : (expf(x) - 1.f); }

// ---------------- CSR build ----------------

__global__ void hist_kernel(const int* __restrict__ dstArr, int* __restrict__ deg) {
    int e = blockIdx.x * 256 + threadIdx.x;
    if (e >= ET) return;
    int d = (e < N_EDGES) ? dstArr[e] : (e - N_EDGES);
    atomicAdd(&deg[d], 1);
}

// single ladder: 1024 threads x CH=64 covers 65536 >= 50000
__global__ __launch_bounds__(1024) void scan_kernel(const int* __restrict__ deg,
                                                    int* __restrict__ off,
                                                    int* __restrict__ cur, int n) {
    __shared__ int sdata[1024];
    int t = threadIdx.x;
    const int CH = 64;
    int base = t * CH;
    int sum = 0;
    for (int u = 0; u < CH; ++u) {
        int ix = base + u;
        sum += (ix < n) ? deg[ix] : 0;
    }
    sdata[t] = sum;
    __syncthreads();
    for (int o = 1; o < 1024; o <<= 1) {
        int x = (t >= o) ? sdata[t - o] : 0;
        __syncthreads();
        sdata[t] += x;
        __syncthreads();
    }
    int run = sdata[t] - sum;   // exclusive prefix
    for (int u = 0; u < CH; ++u) {
        int ix = base + u;
        if (ix < n) {
            off[ix] = run; cur[ix] = run;
            run += deg[ix];
        }
    }
    if (t == 1023) off[n] = sdata[1023];
}

__global__ void scatter_kernel(const int* __restrict__ srcArr, const int* __restrict__ dstArr,
                               int* __restrict__ cur, int* __restrict__ csr) {
    int e = blockIdx.x * 256 + threadIdx.x;
    if (e >= ET) return;
    int s, d;
    if (e < N_EDGES) { s = srcArr[e]; d = dstArr[e]; } else { s = d = e - N_EDGES; }
    int pos = atomicAdd(&cur[d], 1);
    csr[pos] = s;
}

// ---------------- templated f32 GEMM: C[M,N] = A[M,K] @ B[K,N] ----------------
// 256 threads; (BM/TM)*(BN/TN)==256; K % BK == 0; N % BN == 0; M ragged (clamped loads, predicated stores)

template<int BM, int BN, int BK, int TM, int TN>
__global__ __launch_bounds__(256) void gemm_t(const float* __restrict__ A,
                                              const float* __restrict__ B,
                                              float* __restrict__ C,
                                              int M, int N, int K) {
    constexpr int TX = BN / TN;
    constexpr int TY = BM / TM;
    static_assert(TX * TY == 256, "thread grid");
    constexpr int LDA = BM + 4;       // pad keeps 16B alignment of rows, breaks pow2 stride
    __shared__ float As[BK][LDA];     // transposed: As[k][m]
    __shared__ float Bs[BK][BN];

    int tid = threadIdx.x;
    int bm = blockIdx.y * BM;
    int bn = blockIdx.x * BN;
    int tx = tid % TX;
    int ty = tid / TX;

    float acc[TM][TN] = {};

    constexpr int AF4 = BM * BK / 4;  // float4 count in A tile
    constexpr int FPR = BK / 4;       // float4 per A row
    constexpr int BF4 = BK * BN / 4;
    constexpr int BPR = BN / 4;

    for (int k0 = 0; k0 < K; k0 += BK) {
#pragma unroll
        for (int f = tid; f < AF4; f += 256) {
            int r = f / FPR, c4 = f % FPR;
            int gr = bm + r; if (gr > M - 1) gr = M - 1;
            float4 v = *(const float4*)(A + (size_t)gr * K + k0 + c4 * 4);
            As[c4 * 4 + 0][r] = v.x;
            As[c4 * 4 + 1][r] = v.y;
            As[c4 * 4 + 2][r] = v.z;
            As[c4 * 4 + 3][r] = v.w;
        }
#pragma unroll
        for (int f = tid; f < BF4; f += 256) {
            int kk = f / BPR, j4 = f % BPR;
            *(float4*)&Bs[kk][j4 * 4] = *(const float4*)(B + (size_t)(k0 + kk) * N + bn + j4 * 4);
        }
        __syncthreads();
#pragma unroll
        for (int kk = 0; kk < BK; ++kk) {
            float a[TM], b[TN];
#pragma unroll
            for (int i = 0; i < TM; i += 4)
                *(float4*)&a[i] = *(const float4*)&As[kk][ty * TM + i];
            if constexpr (TN == 8) {
                *(float4*)&b[0] = *(const float4*)&Bs[kk][tx * 4];
                *(float4*)&b[4] = *(const float4*)&Bs[kk][BN / 2 + tx * 4];
            } else if constexpr (TN == 4) {
                *(float4*)&b[0] = *(const float4*)&Bs[kk][tx * 4];
            } else {
                b[0] = Bs[kk][tx * 2];
                b[1] = Bs[kk][tx * 2 + 1];
            }
#pragma unroll
            for (int i = 0; i < TM; ++i)
#pragma unroll
                for (int jj = 0; jj < TN; ++jj)
                    acc[i][jj] += a[i] * b[jj];
        }
        __syncthreads();
    }
#pragma unroll
    for (int i = 0; i < TM; ++i) {
        int gr = bm + ty * TM + i;
        if (gr >= M) break;
        if constexpr (TN == 8) {
            *(float4*)(C + (size_t)gr * N + bn + tx * 4) = *(float4*)&acc[i][0];
            *(float4*)(C + (size_t)gr * N + bn + BN / 2 + tx * 4) = *(float4*)&acc[i][4];
        } else if constexpr (TN == 4) {
            *(float4*)(C + (size_t)gr * N + bn + tx * 4) = *(float4*)&acc[i][0];
        } else {
            *(float2*)(C + (size_t)gr * N + bn + tx * 2) = *(float2*)&acc[i][0];
        }
    }
}

// ---------------- per-node attention coefficients ----------------

__global__ void alpha_kernel(const float* __restrict__ h, const float* __restrict__ a_src,
                             const float* __restrict__ a_dst, float* __restrict__ as,
                             float* __restrict__ ad, int n, int H, int C) {
    int t = blockIdx.x * 256 + threadIdx.x;
    if (t >= n * H) return;
    int hh = t % H;
    const float* hp  = h + (size_t)t * C;
    const float* asp = a_src + hh * C;
    const float* adp = a_dst + hh * C;
    float s1 = 0.f, s2 = 0.f;
    for (int c = 0; c < C; c += 4) {
        float4 hv = *(const float4*)(hp + c);
        float4 sv = *(const float4*)(asp + c);
        float4 dv = *(const float4*)(adp + c);
        s1 += hv.x * sv.x + hv.y * sv.y + hv.z * sv.z + hv.w * sv.w;
        s2 += hv.x * dv.x + hv.y * dv.y + hv.z * dv.z + hv.w * dv.w;
    }
    as[t] = s1;
    ad[t] = s2;
}

// ---------------- layer 1 aggregation: H=8, C=32, wave per node, online softmax ----------------

__global__ __launch_bounds__(256) void agg1_kernel(const int* __restrict__ off, const int* __restrict__ csr,
                                                   const float* __restrict__ h, const float* __restrict__ as,
                                                   const float* __restrict__ ad, const float* __restrict__ bias,
                                                   float* __restrict__ out) {
    int node = blockIdx.x * 4 + (threadIdx.x >> 6);
    if (node >= N_NODES) return;
    int lane = threadIdx.x & 63;
    int hh = lane >> 3;
    int j  = lane & 7;
    int s0 = off[node];
    int deg = off[node + 1] - s0;
    float adv = ad[node * H1 + hh];
    int myidx = (lane < deg) ? csr[s0 + lane] : 0;

    float m = -INFINITY, dsum = 0.f;
    float4 acc = make_float4(0.f, 0.f, 0.f, 0.f);
    int i = 0;
    for (; i + 2 <= deg; i += 2) {
        int sA = (i     < 64) ? __shfl(myidx, i)     : csr[s0 + i];
        int sB = (i + 1 < 64) ? __shfl(myidx, i + 1) : csr[s0 + i + 1];
        float4 hA = *(const float4*)(h + (size_t)sA * D1 + hh * C1 + j * 4);
        float4 hB = *(const float4*)(h + (size_t)sB * D1 + hh * C1 + j * 4);
        float eA = lrelu(as[sA * H1 + hh] + adv);
        float eB = lrelu(as[sB * H1 + hh] + adv);
        float mn = fmaxf(m, fmaxf(eA, eB));
        float scale = __expf(m - mn);          // 0 on first iter (m=-inf)
        float wA = __expf(eA - mn);
        float wB = __expf(eB - mn);
        dsum = dsum * scale + wA + wB;
        acc.x = acc.x * scale + wA * hA.x + wB * hB.x;
        acc.y = acc.y * scale + wA * hA.y + wB * hB.y;
        acc.z = acc.z * scale + wA * hA.z + wB * hB.z;
        acc.w = acc.w * scale + wA * hA.w + wB * hB.w;
        m = mn;
    }
    if (i < deg) {
        int sA = (i < 64) ? __shfl(myidx, i) : csr[s0 + i];
        float4 hA = *(const float4*)(h + (size_t)sA * D1 + hh * C1 + j * 4);
        float eA = lrelu(as[sA * H1 + hh] + adv);
        float mn = fmaxf(m, eA);
        float scale = __expf(m - mn);
        float wA = __expf(eA - mn);
        dsum = dsum * scale + wA;
        acc.x = acc.x * scale + wA * hA.x;
        acc.y = acc.y * scale + wA * hA.y;
        acc.z = acc.z * scale + wA * hA.z;
        acc.w = acc.w * scale + wA * hA.w;
    }
    float inv = 1.f / (dsum + 1e-16f);
    int ob = node * D1 + hh * C1 + j * 4;
    const float* bp = bias + hh * C1 + j * 4;
    float4 r;
    r.x = eluf(acc.x * inv + bp[0]);
    r.y = eluf(acc.y * inv + bp[1]);
    r.z = eluf(acc.z * inv + bp[2]);
    r.w = eluf(acc.w * inv + bp[3]);
    *(float4*)(out + ob) = r;
}

// ---------------- layer 2 aggregation: H=1, C=32, wave per node, online softmax ----------------
// lane = c + 32*half; half h processes edges i ≡ h (mod 2); merge at end

__global__ __launch_bounds__(256) void agg32_kernel(const int* __restrict__ off, const int* __restrict__ csr,
                                                    const float* __restrict__ h, const float* __restrict__ as,
                                                    const float* __restrict__ ad, const float* __restrict__ bias,
                                                    float* __restrict__ out) {
    int node = blockIdx.x * 4 + (threadIdx.x >> 6);
    if (node >= N_NODES) return;
    int lane = threadIdx.x & 63;
    int c = lane & 31;
    int half = lane >> 5;
    int s0 = off[node];
    int deg = off[node + 1] - s0;
    float adv = ad[node];
    int myidx = (lane < deg) ? csr[s0 + lane] : 0;

    float m = -INFINITY, dsum = 0.f, acc = 0.f;
    for (int i = half; i < deg; i += 2) {
        int s = (i < 64) ? __shfl(myidx, i) : csr[s0 + i];
        float hv = h[(size_t)s * C2 + c];
        float e = lrelu(as[s] + adv);
        float mn = fmaxf(m, e);
        float scale = __expf(m - mn);
        float w = __expf(e - mn);
        dsum = dsum * scale + w;
        acc  = acc  * scale + w * hv;
        m = mn;
    }
    // merge halves
    float mo = __shfl_xor(m, 32);
    float Mx = fmaxf(m, mo);
    float sc = __expf(m - Mx);          // 0 if this half saw no edges
    dsum *= sc; acc *= sc;
    dsum += __shfl_xor(dsum, 32);
    acc  += __shfl_xor(acc, 32);
    if (half == 0) {
        float r = acc / (dsum + 1e-16f) + bias[c];
        out[(size_t)node * C2 + c] = eluf(r);
    }
}

// ---------------- layer 3 aggregation: H=1, C=64, wave per node, online softmax, no ELU ----------------

__global__ __launch_bounds__(256) void agg64_kernel(const int* __restrict__ off, const int* __restrict__ csr,
                                                    const float* __restrict__ h, const float* __restrict__ as,
                                                    const float* __restrict__ ad, const float* __restrict__ bias,
                                                    float* __restrict__ out) {
    int node = blockIdx.x * 4 + (threadIdx.x >> 6);
    if (node >= N_NODES) return;
    int lane = threadIdx.x & 63;
    int s0 = off[node];
    int deg = off[node + 1] - s0;
    float adv = ad[node];
    int myidx = (lane < deg) ? csr[s0 + lane] : 0;

    float m = -INFINITY, dsum = 0.f, acc = 0.f;
    int i = 0;
    for (; i + 2 <= deg; i += 2) {
        int sA = (i     < 64) ? __shfl(myidx, i)     : csr[s0 + i];
        int sB = (i + 1 < 64) ? __shfl(myidx, i + 1) : csr[s0 + i + 1];
        float hA = h[(size_t)sA * C3 + lane];
        float hB = h[(size_t)sB * C3 + lane];
        float eA = lrelu(as[sA] + adv);
        float eB = lrelu(as[sB] + adv);
        float mn = fmaxf(m, fmaxf(eA, eB));
        float scale = __expf(m - mn);
        float wA = __expf(eA - mn);
        float wB = __expf(eB - mn);
        dsum = dsum * scale + wA + wB;
        acc  = acc  * scale + wA * hA + wB * hB;
        m = mn;
    }
    if (i < deg) {
        int s = (i < 64) ? __shfl(myidx, i) : csr[s0 + i];
        float hv = h[(size_t)s * C3 + lane];
        float e = lrelu(as[s] + adv);
        float mn = fmaxf(m, e);
        float scale = __expf(m - mn);
        float w = __expf(e - mn);
        dsum = dsum * scale + w;
        acc  = acc  * scale + w * hv;
    }
    out[(size_t)node * C3 + lane] = acc / (dsum + 1e-16f) + bias[lane];
}

// ---------------- launch ----------------

extern "C" void kernel_launch(void* const* d_in, const int* in_sizes, int n_in,
                              void* d_out, int out_size, void* d_ws, size_t ws_size,
                              hipStream_t stream) {
    const float* x   = (const float*)d_in[0];
    const int*   ei  = (const int*)d_in[1];
    const float* W1  = (const float*)d_in[2];
    const float* aS1 = (const float*)d_in[3];
    const float* aD1 = (const float*)d_in[4];
    const float* b1  = (const float*)d_in[5];
    const float* W2  = (const float*)d_in[6];
    const float* aS2 = (const float*)d_in[7];
    const float* aD2 = (const float*)d_in[8];
    const float* b2  = (const float*)d_in[9];
    const float* W3  = (const float*)d_in[10];
    const float* aS3 = (const float*)d_in[11];
    const float* aD3 = (const float*)d_in[12];
    const float* b3  = (const float*)d_in[13];
    float* out = (float*)d_out;

    char* p = (char*)d_ws;
    auto alloc = [&](size_t bytes) -> void* {
        void* r = (void*)p;
        p += (bytes + 255) & ~(size_t)255;
        return r;
    };
    float* bufA = (float*)alloc((size_t)N_NODES * D1 * 4);
    float* bufB = (float*)alloc((size_t)N_NODES * D1 * 4);
    int*   deg  = (int*)alloc((size_t)N_NODES * 4);
    int*   off  = (int*)alloc((size_t)(N_NODES + 1) * 4);
    int*   cur  = (int*)alloc((size_t)N_NODES * 4);
    int*   csr  = (int*)alloc((size_t)ET * 4);
    float* asb  = (float*)alloc((size_t)N_NODES * H1 * 4);
    float* adb  = (float*)alloc((size_t)N_NODES * H1 * 4);

    const int* srcArr = ei;
    const int* dstArr = ei + N_EDGES;

    // --- CSR build ---
    hipMemsetAsync(deg, 0, (size_t)N_NODES * 4, stream);
    int eb = (ET + 255) / 256;
    hist_kernel<<<eb, 256, 0, stream>>>(dstArr, deg);
    scan_kernel<<<1, 1024, 0, stream>>>(deg, off, cur, N_NODES);
    scatter_kernel<<<eb, 256, 0, stream>>>(srcArr, dstArr, cur, csr);

    int nb4 = (N_NODES + 3) / 4;

    // --- layer 1: x[50000,128] @ W1[128,256] ---
    gemm_t<128, 128, 16, 8, 8><<<dim3(D1 / 128, (N_NODES + 127) / 128), 256, 0, stream>>>(x, W1, bufA, N_NODES, D1, F0);
    alpha_kernel<<<(N_NODES * H1 + 255) / 256, 256, 0, stream>>>(bufA, aS1, aD1, asb, adb, N_NODES, H1, C1);
    agg1_kernel<<<nb4, 256, 0, stream>>>(off, csr, bufA, asb, adb, b1, bufB);

    // --- layer 2: h[50000,256] @ W2[256,32] ---
    gemm_t<64, 32, 32, 4, 2><<<dim3(1, (N_NODES + 63) / 64), 256, 0, stream>>>(bufB, W2, bufA, N_NODES, C2, D1);
    alpha_kernel<<<(N_NODES + 255) / 256, 256, 0, stream>>>(bufA, aS2, aD2, asb, adb, N_NODES, 1, C2);
    agg32_kernel<<<nb4, 256, 0, stream>>>(off, csr, bufA, asb, adb, b2, bufB);

    // --- layer 3: h[50000,32] @ W3[32,64] ---
    gemm_t<64, 64, 32, 4, 4><<<dim3(1, (N_NODES + 63) / 64), 256, 0, stream>>>(bufB, W3, bufA, N_NODES, C3, C2);
    alpha_kernel<<<(N_NODES + 255) / 256, 256, 0, stream>>>(bufA, aS3, aD3, asb, adb, N_NODES, 1, C3);
    agg64_kernel<<<nb4, 256, 0, stream>>>(off, csr, bufA, asb, adb, b3, out);
}

// Round 5
// 639.700 us; speedup vs baseline: 1.0574x; 1.0083x over previous
//
#include <hip/hip_runtime.h>
#include <hip/hip_bf16.h>
#include <math.h>

#define N_NODES 50000
#define N_EDGES 800000
#define ET (N_EDGES + N_NODES)   // with self loops = 850000
#define F0 128
#define H1 8
#define C1 32
#define D1 (H1*C1)               // 256
#define C2 32
#define C3 64

__device__ __forceinline__ float lrelu(float x) { return x >= 0.f ? x : 0.2f * x; }
__device__ __forceinline__ float eluf(float x)  { return x > 0.f ? x : (expf(x) - 1.f); }

// ---------------- CSR build ----------------

__global__ void hist_kernel(const int* __restrict__ dstArr, int* __restrict__ deg) {
    int e = blockIdx.x * 256 + threadIdx.x;
    if (e >= ET) return;
    int d = (e < N_EDGES) ? dstArr[e] : (e - N_EDGES);
    atomicAdd(&deg[d], 1);
}

__global__ __launch_bounds__(1024) void scan_kernel(const int* __restrict__ deg,
                                                    int* __restrict__ off,
                                                    int* __restrict__ cur, int n) {
    __shared__ int sdata[1024];
    int t = threadIdx.x;
    const int CH = 64;
    int base = t * CH;
    int sum = 0;
    for (int u = 0; u < CH; ++u) {
        int ix = base + u;
        sum += (ix < n) ? deg[ix] : 0;
    }
    sdata[t] = sum;
    __syncthreads();
    for (int o = 1; o < 1024; o <<= 1) {
        int x = (t >= o) ? sdata[t - o] : 0;
        __syncthreads();
        sdata[t] += x;
        __syncthreads();
    }
    int run = sdata[t] - sum;   // exclusive prefix
    for (int u = 0; u < CH; ++u) {
        int ix = base + u;
        if (ix < n) {
            off[ix] = run; cur[ix] = run;
            run += deg[ix];
        }
    }
    if (t == 1023) off[n] = sdata[1023];
}

__global__ void scatter_kernel(const int* __restrict__ srcArr, const int* __restrict__ dstArr,
                               int* __restrict__ cur, int* __restrict__ csr) {
    int e = blockIdx.x * 256 + threadIdx.x;
    if (e >= ET) return;
    int s, d;
    if (e < N_EDGES) { s = srcArr[e]; d = dstArr[e]; } else { s = d = e - N_EDGES; }
    int pos = atomicAdd(&cur[d], 1);
    csr[pos] = s;
}

// ---------------- templated f32 GEMM ----------------

template<int BM, int BN, int BK, int TM, int TN>
__global__ __launch_bounds__(256) void gemm_t(const float* __restrict__ A,
                                              const float* __restrict__ B,
                                              float* __restrict__ C,
                                              int M, int N, int K) {
    constexpr int TX = BN / TN;
    constexpr int TY = BM / TM;
    static_assert(TX * TY == 256, "thread grid");
    constexpr int LDA = BM + 4;
    __shared__ float As[BK][LDA];
    __shared__ float Bs[BK][BN];

    int tid = threadIdx.x;
    int bm = blockIdx.y * BM;
    int bn = blockIdx.x * BN;
    int tx = tid % TX;
    int ty = tid / TX;

    float acc[TM][TN] = {};

    constexpr int AF4 = BM * BK / 4;
    constexpr int FPR = BK / 4;
    constexpr int BF4 = BK * BN / 4;
    constexpr int BPR = BN / 4;

    for (int k0 = 0; k0 < K; k0 += BK) {
#pragma unroll
        for (int f = tid; f < AF4; f += 256) {
            int r = f / FPR, c4 = f % FPR;
            int gr = bm + r; if (gr > M - 1) gr = M - 1;
            float4 v = *(const float4*)(A + (size_t)gr * K + k0 + c4 * 4);
            As[c4 * 4 + 0][r] = v.x;
            As[c4 * 4 + 1][r] = v.y;
            As[c4 * 4 + 2][r] = v.z;
            As[c4 * 4 + 3][r] = v.w;
        }
#pragma unroll
        for (int f = tid; f < BF4; f += 256) {
            int kk = f / BPR, j4 = f % BPR;
            *(float4*)&Bs[kk][j4 * 4] = *(const float4*)(B + (size_t)(k0 + kk) * N + bn + j4 * 4);
        }
        __syncthreads();
#pragma unroll
        for (int kk = 0; kk < BK; ++kk) {
            float a[TM], b[TN];
#pragma unroll
            for (int i = 0; i < TM; i += 4)
                *(float4*)&a[i] = *(const float4*)&As[kk][ty * TM + i];
            if constexpr (TN == 8) {
                *(float4*)&b[0] = *(const float4*)&Bs[kk][tx * 4];
                *(float4*)&b[4] = *(const float4*)&Bs[kk][BN / 2 + tx * 4];
            } else if constexpr (TN == 4) {
                *(float4*)&b[0] = *(const float4*)&Bs[kk][tx * 4];
            } else {
                b[0] = Bs[kk][tx * 2];
                b[1] = Bs[kk][tx * 2 + 1];
            }
#pragma unroll
            for (int i = 0; i < TM; ++i)
#pragma unroll
                for (int jj = 0; jj < TN; ++jj)
                    acc[i][jj] += a[i] * b[jj];
        }
        __syncthreads();
    }
#pragma unroll
    for (int i = 0; i < TM; ++i) {
        int gr = bm + ty * TM + i;
        if (gr >= M) break;
        if constexpr (TN == 8) {
            *(float4*)(C + (size_t)gr * N + bn + tx * 4) = *(float4*)&acc[i][0];
            *(float4*)(C + (size_t)gr * N + bn + BN / 2 + tx * 4) = *(float4*)&acc[i][4];
        } else if constexpr (TN == 4) {
            *(float4*)(C + (size_t)gr * N + bn + tx * 4) = *(float4*)&acc[i][0];
        } else {
            *(float2*)(C + (size_t)gr * N + bn + tx * 2) = *(float2*)&acc[i][0];
        }
    }
}

// ---------------- per-node attention coefficients ----------------

__global__ void alpha_kernel(const float* __restrict__ h, const float* __restrict__ a_src,
                             const float* __restrict__ a_dst, float* __restrict__ as,
                             float* __restrict__ ad, int n, int H, int C) {
    int t = blockIdx.x * 256 + threadIdx.x;
    if (t >= n * H) return;
    int hh = t % H;
    const float* hp  = h + (size_t)t * C;
    const float* asp = a_src + hh * C;
    const float* adp = a_dst + hh * C;
    float s1 = 0.f, s2 = 0.f;
    for (int c = 0; c < C; c += 4) {
        float4 hv = *(const float4*)(hp + c);
        float4 sv = *(const float4*)(asp + c);
        float4 dv = *(const float4*)(adp + c);
        s1 += hv.x * sv.x + hv.y * sv.y + hv.z * sv.z + hv.w * sv.w;
        s2 += hv.x * dv.x + hv.y * dv.y + hv.z * dv.z + hv.w * dv.w;
    }
    as[t] = s1;
    ad[t] = s2;
}

// ---------------- layer 1 aggregation: H=8, C=32, wave per node ----------------
// R1-proven 3-pass structure (max pass + dsum pass verbatim). Pass 3 is a pure
// gather-FMA loop, unroll 4, reading csr directly (no shfl index cache).

__global__ __launch_bounds__(256) void agg1_kernel(const int* __restrict__ off, const int* __restrict__ csr,
                                                   const float* __restrict__ h, const float* __restrict__ as,
                                                   const float* __restrict__ ad, const float* __restrict__ bias,
                                                   float* __restrict__ out) {
    int node = blockIdx.x * 4 + (threadIdx.x >> 6);
    if (node >= N_NODES) return;
    int lane = threadIdx.x & 63;
    int hh = lane >> 3;
    int j  = lane & 7;
    int s0 = off[node];
    int deg = off[node + 1] - s0;
    float adv = ad[node * H1 + hh];
    int myidx = (lane < deg) ? csr[s0 + lane] : 0;

    // pass 1: exact max for this head (verbatim R1)
    float m = -INFINITY;
    for (int i = j; i < deg; i += 8) {
        int s = (i < 64) ? __shfl(myidx, i) : csr[s0 + i];
        float e = lrelu(as[s * H1 + hh] + adv);
        m = fmaxf(m, e);
    }
    m = fmaxf(m, __shfl_xor(m, 1));
    m = fmaxf(m, __shfl_xor(m, 2));
    m = fmaxf(m, __shfl_xor(m, 4));

    // pass 2: denominator (verbatim R1)
    float dsum = 0.f;
    for (int i = j; i < deg; i += 8) {
        int s = (i < 64) ? __shfl(myidx, i) : csr[s0 + i];
        float e = lrelu(as[s * H1 + hh] + adv);
        dsum += __expf(e - m);
    }
    dsum += __shfl_xor(dsum, 1);
    dsum += __shfl_xor(dsum, 2);
    dsum += __shfl_xor(dsum, 4);
    float inv = 1.f / (dsum + 1e-16f);

    // pass 3: pure gather-FMA, unroll 4, direct csr reads (no shfl)
    float4 acc = make_float4(0.f, 0.f, 0.f, 0.f);
    int i = 0;
    for (; i + 4 <= deg; i += 4) {
        int sa = csr[s0 + i];
        int sb = csr[s0 + i + 1];
        int sc = csr[s0 + i + 2];
        int sd = csr[s0 + i + 3];
        float4 ha = *(const float4*)(h + (size_t)sa * D1 + hh * C1 + j * 4);
        float4 hb = *(const float4*)(h + (size_t)sb * D1 + hh * C1 + j * 4);
        float4 hc = *(const float4*)(h + (size_t)sc * D1 + hh * C1 + j * 4);
        float4 hd = *(const float4*)(h + (size_t)sd * D1 + hh * C1 + j * 4);
        float wa = __expf(lrelu(as[sa * H1 + hh] + adv) - m);
        float wb = __expf(lrelu(as[sb * H1 + hh] + adv) - m);
        float wc = __expf(lrelu(as[sc * H1 + hh] + adv) - m);
        float wd = __expf(lrelu(as[sd * H1 + hh] + adv) - m);
        acc.x += wa * ha.x + wb * hb.x + wc * hc.x + wd * hd.x;
        acc.y += wa * ha.y + wb * hb.y + wc * hc.y + wd * hd.y;
        acc.z += wa * ha.z + wb * hb.z + wc * hc.z + wd * hd.z;
        acc.w += wa * ha.w + wb * hb.w + wc * hc.w + wd * hd.w;
    }
    for (; i < deg; ++i) {
        int s = csr[s0 + i];
        float4 hv = *(const float4*)(h + (size_t)s * D1 + hh * C1 + j * 4);
        float w = __expf(lrelu(as[s * H1 + hh] + adv) - m);
        acc.x += w * hv.x; acc.y += w * hv.y; acc.z += w * hv.z; acc.w += w * hv.w;
    }
    int ob = node * D1 + hh * C1 + j * 4;
    const float* bp = bias + hh * C1 + j * 4;
    float4 r;
    r.x = eluf(acc.x * inv + bp[0]);
    r.y = eluf(acc.y * inv + bp[1]);
    r.z = eluf(acc.z * inv + bp[2]);
    r.w = eluf(acc.w * inv + bp[3]);
    *(float4*)(out + ob) = r;
}

// ---------------- layer 2 aggregation: H=1, C=32, wave per node, online softmax ----------------
// verbatim R2 (passed)

__global__ __launch_bounds__(256) void agg32_kernel(const int* __restrict__ off, const int* __restrict__ csr,
                                                    const float* __restrict__ h, const float* __restrict__ as,
                                                    const float* __restrict__ ad, const float* __restrict__ bias,
                                                    float* __restrict__ out) {
    int node = blockIdx.x * 4 + (threadIdx.x >> 6);
    if (node >= N_NODES) return;
    int lane = threadIdx.x & 63;
    int c = lane & 31;
    int half = lane >> 5;
    int s0 = off[node];
    int deg = off[node + 1] - s0;
    float adv = ad[node];
    int myidx = (lane < deg) ? csr[s0 + lane] : 0;

    float m = -INFINITY, dsum = 0.f, acc = 0.f;
    for (int i = half; i < deg; i += 2) {
        int s = (i < 64) ? __shfl(myidx, i) : csr[s0 + i];
        float hv = h[(size_t)s * C2 + c];
        float e = lrelu(as[s] + adv);
        float mn = fmaxf(m, e);
        float scale = __expf(m - mn);
        float w = __expf(e - mn);
        dsum = dsum * scale + w;
        acc  = acc  * scale + w * hv;
        m = mn;
    }
    // merge halves
    float mo = __shfl_xor(m, 32);
    float Mx = fmaxf(m, mo);
    float sc = __expf(m - Mx);          // 0 if this half saw no edges
    dsum *= sc; acc *= sc;
    dsum += __shfl_xor(dsum, 32);
    acc  += __shfl_xor(acc, 32);
    if (half == 0) {
        float r = acc / (dsum + 1e-16f) + bias[c];
        out[(size_t)node * C2 + c] = eluf(r);
    }
}

// ---------------- layer 3 aggregation: H=1, C=64, wave per node, online softmax, no ELU ----------------
// verbatim R2 (passed)

__global__ __launch_bounds__(256) void agg64_kernel(const int* __restrict__ off, const int* __restrict__ csr,
                                                    const float* __restrict__ h, const float* __restrict__ as,
                                                    const float* __restrict__ ad, const float* __restrict__ bias,
                                                    float* __restrict__ out) {
    int node = blockIdx.x * 4 + (threadIdx.x >> 6);
    if (node >= N_NODES) return;
    int lane = threadIdx.x & 63;
    int s0 = off[node];
    int deg = off[node + 1] - s0;
    float adv = ad[node];
    int myidx = (lane < deg) ? csr[s0 + lane] : 0;

    float m = -INFINITY, dsum = 0.f, acc = 0.f;
    int i = 0;
    for (; i + 2 <= deg; i += 2) {
        int sA = (i     < 64) ? __shfl(myidx, i)     : csr[s0 + i];
        int sB = (i + 1 < 64) ? __shfl(myidx, i + 1) : csr[s0 + i + 1];
        float hA = h[(size_t)sA * C3 + lane];
        float hB = h[(size_t)sB * C3 + lane];
        float eA = lrelu(as[sA] + adv);
        float eB = lrelu(as[sB] + adv);
        float mn = fmaxf(m, fmaxf(eA, eB));
        float scale = __expf(m - mn);
        float wA = __expf(eA - mn);
        float wB = __expf(eB - mn);
        dsum = dsum * scale + wA + wB;
        acc  = acc  * scale + wA * hA + wB * hB;
        m = mn;
    }
    if (i < deg) {
        int s = (i < 64) ? __shfl(myidx, i) : csr[s0 + i];
        float hv = h[(size_t)s * C3 + lane];
        float e = lrelu(as[s] + adv);
        float mn = fmaxf(m, e);
        float scale = __expf(m - mn);
        float w = __expf(e - mn);
        dsum = dsum * scale + w;
        acc  = acc  * scale + w * hv;
    }
    out[(size_t)node * C3 + lane] = acc / (dsum + 1e-16f) + bias[lane];
}

// ---------------- launch ----------------

extern "C" void kernel_launch(void* const* d_in, const int* in_sizes, int n_in,
                              void* d_out, int out_size, void* d_ws, size_t ws_size,
                              hipStream_t stream) {
    const float* x   = (const float*)d_in[0];
    const int*   ei  = (const int*)d_in[1];
    const float* W1  = (const float*)d_in[2];
    const float* aS1 = (const float*)d_in[3];
    const float* aD1 = (const float*)d_in[4];
    const float* b1  = (const float*)d_in[5];
    const float* W2  = (const float*)d_in[6];
    const float* aS2 = (const float*)d_in[7];
    const float* aD2 = (const float*)d_in[8];
    const float* b2  = (const float*)d_in[9];
    const float* W3  = (const float*)d_in[10];
    const float* aS3 = (const float*)d_in[11];
    const float* aD3 = (const float*)d_in[12];
    const float* b3  = (const float*)d_in[13];
    float* out = (float*)d_out;

    char* p = (char*)d_ws;
    auto alloc = [&](size_t bytes) -> void* {
        void* r = (void*)p;
        p += (bytes + 255) & ~(size_t)255;
        return r;
    };
    float* bufA = (float*)alloc((size_t)N_NODES * D1 * 4);
    float* bufB = (float*)alloc((size_t)N_NODES * D1 * 4);
    int*   deg  = (int*)alloc((size_t)N_NODES * 4);
    int*   off  = (int*)alloc((size_t)(N_NODES + 1) * 4);
    int*   cur  = (int*)alloc((size_t)N_NODES * 4);
    int*   csr  = (int*)alloc((size_t)ET * 4);
    float* asb  = (float*)alloc((size_t)N_NODES * H1 * 4);
    float* adb  = (float*)alloc((size_t)N_NODES * H1 * 4);

    const int* srcArr = ei;
    const int* dstArr = ei + N_EDGES;

    // --- CSR build ---
    hipMemsetAsync(deg, 0, (size_t)N_NODES * 4, stream);
    int eb = (ET + 255) / 256;
    hist_kernel<<<eb, 256, 0, stream>>>(dstArr, deg);
    scan_kernel<<<1, 1024, 0, stream>>>(deg, off, cur, N_NODES);
    scatter_kernel<<<eb, 256, 0, stream>>>(srcArr, dstArr, cur, csr);

    int nb4 = (N_NODES + 3) / 4;

    // --- layer 1 ---
    gemm_t<128, 128, 16, 8, 8><<<dim3(D1 / 128, (N_NODES + 127) / 128), 256, 0, stream>>>(x, W1, bufA, N_NODES, D1, F0);
    alpha_kernel<<<(N_NODES * H1 + 255) / 256, 256, 0, stream>>>(bufA, aS1, aD1, asb, adb, N_NODES, H1, C1);
    agg1_kernel<<<nb4, 256, 0, stream>>>(off, csr, bufA, asb, adb, b1, bufB);

    // --- layer 2 ---
    gemm_t<64, 32, 32, 4, 2><<<dim3(1, (N_NODES + 63) / 64), 256, 0, stream>>>(bufB, W2, bufA, N_NODES, C2, D1);
    alpha_kernel<<<(N_NODES + 255) / 256, 256, 0, stream>>>(bufA, aS2, aD2, asb, adb, N_NODES, 1, C2);
    agg32_kernel<<<nb4, 256, 0, stream>>>(off, csr, bufA, asb, adb, b2, bufB);

    // --- layer 3 ---
    gemm_t<64, 64, 32, 4, 4><<<dim3(1, (N_NODES + 63) / 64), 256, 0, stream>>>(bufB, W3, bufA, N_NODES, C3, C2);
    alpha_kernel<<<(N_NODES + 255) / 256, 256, 0, stream>>>(bufA, aS3, aD3, asb, adb, N_NODES, 1, C3);
    agg64_kernel<<<nb4, 256, 0, stream>>>(off, csr, bufA, asb, adb, b3, out);
}

// Round 6
// 621.133 us; speedup vs baseline: 1.0890x; 1.0299x over previous
//
#include <hip/hip_runtime.h>
#include <hip/hip_bf16.h>
#include <math.h>

#define N_NODES 50000
#define N_EDGES 800000
#define ET (N_EDGES + N_NODES)   // with self loops = 850000
#define F0 128
#define H1 8
#define C1 32
#define D1 (H1*C1)               // 256
#define C2 32
#define C3 64

__device__ __forceinline__ float lrelu(float x) { return x >= 0.f ? x : 0.2f * x; }
__device__ __forceinline__ float eluf(float x)  { return x > 0.f ? x : (expf(x) - 1.f); }

// ---------------- CSR build ----------------

__global__ void hist_kernel(const int* __restrict__ dstArr, int* __restrict__ deg) {
    int e = blockIdx.x * 256 + threadIdx.x;
    if (e >= ET) return;
    int d = (e < N_EDGES) ? dstArr[e] : (e - N_EDGES);
    atomicAdd(&deg[d], 1);
}

__global__ __launch_bounds__(1024) void scan_kernel(const int* __restrict__ deg,
                                                    int* __restrict__ off,
                                                    int* __restrict__ cur, int n) {
    __shared__ int sdata[1024];
    int t = threadIdx.x;
    const int CH = 64;
    int base = t * CH;
    int sum = 0;
    for (int u = 0; u < CH; ++u) {
        int ix = base + u;
        sum += (ix < n) ? deg[ix] : 0;
    }
    sdata[t] = sum;
    __syncthreads();
    for (int o = 1; o < 1024; o <<= 1) {
        int x = (t >= o) ? sdata[t - o] : 0;
        __syncthreads();
        sdata[t] += x;
        __syncthreads();
    }
    int run = sdata[t] - sum;   // exclusive prefix
    for (int u = 0; u < CH; ++u) {
        int ix = base + u;
        if (ix < n) {
            off[ix] = run; cur[ix] = run;
            run += deg[ix];
        }
    }
    if (t == 1023) off[n] = sdata[1023];
}

__global__ void scatter_kernel(const int* __restrict__ srcArr, const int* __restrict__ dstArr,
                               int* __restrict__ cur, int* __restrict__ csr) {
    int e = blockIdx.x * 256 + threadIdx.x;
    if (e >= ET) return;
    int s, d;
    if (e < N_EDGES) { s = srcArr[e]; d = dstArr[e]; } else { s = d = e - N_EDGES; }
    int pos = atomicAdd(&cur[d], 1);
    csr[pos] = s;
}

// ---------------- templated f32 GEMM ----------------

template<int BM, int BN, int BK, int TM, int TN>
__global__ __launch_bounds__(256) void gemm_t(const float* __restrict__ A,
                                              const float* __restrict__ B,
                                              float* __restrict__ C,
                                              int M, int N, int K) {
    constexpr int TX = BN / TN;
    constexpr int TY = BM / TM;
    static_assert(TX * TY == 256, "thread grid");
    constexpr int LDA = BM + 4;
    __shared__ float As[BK][LDA];
    __shared__ float Bs[BK][BN];

    int tid = threadIdx.x;
    int bm = blockIdx.y * BM;
    int bn = blockIdx.x * BN;
    int tx = tid % TX;
    int ty = tid / TX;

    float acc[TM][TN] = {};

    constexpr int AF4 = BM * BK / 4;
    constexpr int FPR = BK / 4;
    constexpr int BF4 = BK * BN / 4;
    constexpr int BPR = BN / 4;

    for (int k0 = 0; k0 < K; k0 += BK) {
#pragma unroll
        for (int f = tid; f < AF4; f += 256) {
            int r = f / FPR, c4 = f % FPR;
            int gr = bm + r; if (gr > M - 1) gr = M - 1;
            float4 v = *(const float4*)(A + (size_t)gr * K + k0 + c4 * 4);
            As[c4 * 4 + 0][r] = v.x;
            As[c4 * 4 + 1][r] = v.y;
            As[c4 * 4 + 2][r] = v.z;
            As[c4 * 4 + 3][r] = v.w;
        }
#pragma unroll
        for (int f = tid; f < BF4; f += 256) {
            int kk = f / BPR, j4 = f % BPR;
            *(float4*)&Bs[kk][j4 * 4] = *(const float4*)(B + (size_t)(k0 + kk) * N + bn + j4 * 4);
        }
        __syncthreads();
#pragma unroll
        for (int kk = 0; kk < BK; ++kk) {
            float a[TM], b[TN];
#pragma unroll
            for (int i = 0; i < TM; i += 4)
                *(float4*)&a[i] = *(const float4*)&As[kk][ty * TM + i];
            if constexpr (TN == 8) {
                *(float4*)&b[0] = *(const float4*)&Bs[kk][tx * 4];
                *(float4*)&b[4] = *(const float4*)&Bs[kk][BN / 2 + tx * 4];
            } else if constexpr (TN == 4) {
                *(float4*)&b[0] = *(const float4*)&Bs[kk][tx * 4];
            } else {
                b[0] = Bs[kk][tx * 2];
                b[1] = Bs[kk][tx * 2 + 1];
            }
#pragma unroll
            for (int i = 0; i < TM; ++i)
#pragma unroll
                for (int jj = 0; jj < TN; ++jj)
                    acc[i][jj] += a[i] * b[jj];
        }
        __syncthreads();
    }
#pragma unroll
    for (int i = 0; i < TM; ++i) {
        int gr = bm + ty * TM + i;
        if (gr >= M) break;
        if constexpr (TN == 8) {
            *(float4*)(C + (size_t)gr * N + bn + tx * 4) = *(float4*)&acc[i][0];
            *(float4*)(C + (size_t)gr * N + bn + BN / 2 + tx * 4) = *(float4*)&acc[i][4];
        } else if constexpr (TN == 4) {
            *(float4*)(C + (size_t)gr * N + bn + tx * 4) = *(float4*)&acc[i][0];
        } else {
            *(float2*)(C + (size_t)gr * N + bn + tx * 2) = *(float2*)&acc[i][0];
        }
    }
}

// ---------------- per-node attention coefficients ----------------

__global__ void alpha_kernel(const float* __restrict__ h, const float* __restrict__ a_src,
                             const float* __restrict__ a_dst, float* __restrict__ as,
                             float* __restrict__ ad, int n, int H, int C) {
    int t = blockIdx.x * 256 + threadIdx.x;
    if (t >= n * H) return;
    int hh = t % H;
    const float* hp  = h + (size_t)t * C;
    const float* asp = a_src + hh * C;
    const float* adp = a_dst + hh * C;
    float s1 = 0.f, s2 = 0.f;
    for (int c = 0; c < C; c += 4) {
        float4 hv = *(const float4*)(hp + c);
        float4 sv = *(const float4*)(asp + c);
        float4 dv = *(const float4*)(adp + c);
        s1 += hv.x * sv.x + hv.y * sv.y + hv.z * sv.z + hv.w * sv.w;
        s2 += hv.x * dv.x + hv.y * dv.y + hv.z * dv.z + hv.w * dv.w;
    }
    as[t] = s1;
    ad[t] = s2;
}

// ---------------- layer 1 aggregation: H=8, C=32, wave per node ----------------
// SINGLE pass: w = exp(lrelu(as+ad)) without max subtraction (|e| <= ~15 here,
// exp is safe in f32; softmax ratio is mathematically identical). Each lane
// sees all edges -> per-lane dsum is the full denominator, no reductions.
// Unroll-4 direct csr reads (R5-proven construct).

__global__ __launch_bounds__(256) void agg1_kernel(const int* __restrict__ off, const int* __restrict__ csr,
                                                   const float* __restrict__ h, const float* __restrict__ as,
                                                   const float* __restrict__ ad, const float* __restrict__ bias,
                                                   float* __restrict__ out) {
    int node = blockIdx.x * 4 + (threadIdx.x >> 6);
    if (node >= N_NODES) return;
    int lane = threadIdx.x & 63;
    int hh = lane >> 3;
    int j  = lane & 7;
    int s0 = off[node];
    int deg = off[node + 1] - s0;
    float adv = ad[node * H1 + hh];

    float4 acc = make_float4(0.f, 0.f, 0.f, 0.f);
    float dsum = 0.f;
    int i = 0;
    for (; i + 4 <= deg; i += 4) {
        int sa = csr[s0 + i];
        int sb = csr[s0 + i + 1];
        int sc = csr[s0 + i + 2];
        int sd = csr[s0 + i + 3];
        float4 ha = *(const float4*)(h + (size_t)sa * D1 + hh * C1 + j * 4);
        float4 hb = *(const float4*)(h + (size_t)sb * D1 + hh * C1 + j * 4);
        float4 hc = *(const float4*)(h + (size_t)sc * D1 + hh * C1 + j * 4);
        float4 hd = *(const float4*)(h + (size_t)sd * D1 + hh * C1 + j * 4);
        float wa = __expf(lrelu(as[sa * H1 + hh] + adv));
        float wb = __expf(lrelu(as[sb * H1 + hh] + adv));
        float wc = __expf(lrelu(as[sc * H1 + hh] + adv));
        float wd = __expf(lrelu(as[sd * H1 + hh] + adv));
        dsum += wa + wb + wc + wd;
        acc.x += wa * ha.x + wb * hb.x + wc * hc.x + wd * hd.x;
        acc.y += wa * ha.y + wb * hb.y + wc * hc.y + wd * hd.y;
        acc.z += wa * ha.z + wb * hb.z + wc * hc.z + wd * hd.z;
        acc.w += wa * ha.w + wb * hb.w + wc * hc.w + wd * hd.w;
    }
    for (; i < deg; ++i) {
        int s = csr[s0 + i];
        float4 hv = *(const float4*)(h + (size_t)s * D1 + hh * C1 + j * 4);
        float w = __expf(lrelu(as[s * H1 + hh] + adv));
        dsum += w;
        acc.x += w * hv.x; acc.y += w * hv.y; acc.z += w * hv.z; acc.w += w * hv.w;
    }
    float inv = 1.f / (dsum + 1e-16f);
    int ob = node * D1 + hh * C1 + j * 4;
    const float* bp = bias + hh * C1 + j * 4;
    float4 r;
    r.x = eluf(acc.x * inv + bp[0]);
    r.y = eluf(acc.y * inv + bp[1]);
    r.z = eluf(acc.z * inv + bp[2]);
    r.w = eluf(acc.w * inv + bp[3]);
    *(float4*)(out + ob) = r;
}

// ---------------- layer 2 aggregation: H=1, C=32, wave per node ----------------
// single pass, no max, half-split; exact merge (weights absolute).

__global__ __launch_bounds__(256) void agg32_kernel(const int* __restrict__ off, const int* __restrict__ csr,
                                                    const float* __restrict__ h, const float* __restrict__ as,
                                                    const float* __restrict__ ad, const float* __restrict__ bias,
                                                    float* __restrict__ out) {
    int node = blockIdx.x * 4 + (threadIdx.x >> 6);
    if (node >= N_NODES) return;
    int lane = threadIdx.x & 63;
    int c = lane & 31;
    int half = lane >> 5;
    int s0 = off[node];
    int deg = off[node + 1] - s0;
    float adv = ad[node];

    float acc = 0.f, dsum = 0.f;
    int i = half;
    for (; i + 6 < deg; i += 8) {
        int sa = csr[s0 + i];
        int sb = csr[s0 + i + 2];
        int sc = csr[s0 + i + 4];
        int sd = csr[s0 + i + 6];
        float ha = h[(size_t)sa * C2 + c];
        float hb = h[(size_t)sb * C2 + c];
        float hc = h[(size_t)sc * C2 + c];
        float hd = h[(size_t)sd * C2 + c];
        float wa = __expf(lrelu(as[sa] + adv));
        float wb = __expf(lrelu(as[sb] + adv));
        float wc = __expf(lrelu(as[sc] + adv));
        float wd = __expf(lrelu(as[sd] + adv));
        dsum += wa + wb + wc + wd;
        acc += wa * ha + wb * hb + wc * hc + wd * hd;
    }
    for (; i < deg; i += 2) {
        int s = csr[s0 + i];
        float w = __expf(lrelu(as[s] + adv));
        dsum += w;
        acc += w * h[(size_t)s * C2 + c];
    }
    acc  += __shfl_xor(acc, 32);
    dsum += __shfl_xor(dsum, 32);
    if (half == 0) {
        out[(size_t)node * C2 + c] = eluf(acc / (dsum + 1e-16f) + bias[c]);
    }
}

// ---------------- layer 3 aggregation: H=1, C=64, wave per node, no ELU ----------------
// single pass, no max; every lane sees all edges -> local dsum, no reduce.

__global__ __launch_bounds__(256) void agg64_kernel(const int* __restrict__ off, const int* __restrict__ csr,
                                                    const float* __restrict__ h, const float* __restrict__ as,
                                                    const float* __restrict__ ad, const float* __restrict__ bias,
                                                    float* __restrict__ out) {
    int node = blockIdx.x * 4 + (threadIdx.x >> 6);
    if (node >= N_NODES) return;
    int lane = threadIdx.x & 63;
    int s0 = off[node];
    int deg = off[node + 1] - s0;
    float adv = ad[node];

    float acc = 0.f, dsum = 0.f;
    int i = 0;
    for (; i + 4 <= deg; i += 4) {
        int sa = csr[s0 + i];
        int sb = csr[s0 + i + 1];
        int sc = csr[s0 + i + 2];
        int sd = csr[s0 + i + 3];
        float ha = h[(size_t)sa * C3 + lane];
        float hb = h[(size_t)sb * C3 + lane];
        float hc = h[(size_t)sc * C3 + lane];
        float hd = h[(size_t)sd * C3 + lane];
        float wa = __expf(lrelu(as[sa] + adv));
        float wb = __expf(lrelu(as[sb] + adv));
        float wc = __expf(lrelu(as[sc] + adv));
        float wd = __expf(lrelu(as[sd] + adv));
        dsum += wa + wb + wc + wd;
        acc += wa * ha + wb * hb + wc * hc + wd * hd;
    }
    for (; i < deg; ++i) {
        int s = csr[s0 + i];
        float w = __expf(lrelu(as[s] + adv));
        dsum += w;
        acc += w * h[(size_t)s * C3 + lane];
    }
    out[(size_t)node * C3 + lane] = acc / (dsum + 1e-16f) + bias[lane];
}

// ---------------- launch ----------------

extern "C" void kernel_launch(void* const* d_in, const int* in_sizes, int n_in,
                              void* d_out, int out_size, void* d_ws, size_t ws_size,
                              hipStream_t stream) {
    const float* x   = (const float*)d_in[0];
    const int*   ei  = (const int*)d_in[1];
    const float* W1  = (const float*)d_in[2];
    const float* aS1 = (const float*)d_in[3];
    const float* aD1 = (const float*)d_in[4];
    const float* b1  = (const float*)d_in[5];
    const float* W2  = (const float*)d_in[6];
    const float* aS2 = (const float*)d_in[7];
    const float* aD2 = (const float*)d_in[8];
    const float* b2  = (const float*)d_in[9];
    const float* W3  = (const float*)d_in[10];
    const float* aS3 = (const float*)d_in[11];
    const float* aD3 = (const float*)d_in[12];
    const float* b3  = (const float*)d_in[13];
    float* out = (float*)d_out;

    char* p = (char*)d_ws;
    auto alloc = [&](size_t bytes) -> void* {
        void* r = (void*)p;
        p += (bytes + 255) & ~(size_t)255;
        return r;
    };
    float* bufA = (float*)alloc((size_t)N_NODES * D1 * 4);
    float* bufB = (float*)alloc((size_t)N_NODES * D1 * 4);
    int*   deg  = (int*)alloc((size_t)N_NODES * 4);
    int*   off  = (int*)alloc((size_t)(N_NODES + 1) * 4);
    int*   cur  = (int*)alloc((size_t)N_NODES * 4);
    int*   csr  = (int*)alloc((size_t)ET * 4);
    float* asb  = (float*)alloc((size_t)N_NODES * H1 * 4);
    float* adb  = (float*)alloc((size_t)N_NODES * H1 * 4);

    const int* srcArr = ei;
    const int* dstArr = ei + N_EDGES;

    // --- CSR build ---
    hipMemsetAsync(deg, 0, (size_t)N_NODES * 4, stream);
    int eb = (ET + 255) / 256;
    hist_kernel<<<eb, 256, 0, stream>>>(dstArr, deg);
    scan_kernel<<<1, 1024, 0, stream>>>(deg, off, cur, N_NODES);
    scatter_kernel<<<eb, 256, 0, stream>>>(srcArr, dstArr, cur, csr);

    int nb4 = (N_NODES + 3) / 4;

    // --- layer 1 ---
    gemm_t<128, 128, 16, 8, 8><<<dim3(D1 / 128, (N_NODES + 127) / 128), 256, 0, stream>>>(x, W1, bufA, N_NODES, D1, F0);
    alpha_kernel<<<(N_NODES * H1 + 255) / 256, 256, 0, stream>>>(bufA, aS1, aD1, asb, adb, N_NODES, H1, C1);
    agg1_kernel<<<nb4, 256, 0, stream>>>(off, csr, bufA, asb, adb, b1, bufB);

    // --- layer 2 ---
    gemm_t<64, 32, 32, 4, 2><<<dim3(1, (N_NODES + 63) / 64), 256, 0, stream>>>(bufB, W2, bufA, N_NODES, C2, D1);
    alpha_kernel<<<(N_NODES + 255) / 256, 256, 0, stream>>>(bufA, aS2, aD2, asb, adb, N_NODES, 1, C2);
    agg32_kernel<<<nb4, 256, 0, stream>>>(off, csr, bufA, asb, adb, b2, bufB);

    // --- layer 3 ---
    gemm_t<64, 64, 32, 4, 4><<<dim3(1, (N_NODES + 63) / 64), 256, 0, stream>>>(bufB, W3, bufA, N_NODES, C3, C2);
    alpha_kernel<<<(N_NODES + 255) / 256, 256, 0, stream>>>(bufA, aS3, aD3, asb, adb, N_NODES, 1, C3);
    agg64_kernel<<<nb4, 256, 0, stream>>>(off, csr, bufA, asb, adb, b3, out);
}

// Round 7
// 563.981 us; speedup vs baseline: 1.1994x; 1.1013x over previous
//
#include <hip/hip_runtime.h>
#include <hip/hip_bf16.h>
#include <math.h>

#define N_NODES 50000
#define N_EDGES 800000
#define ET (N_EDGES + N_NODES)   // with self loops = 850000
#define F0 128
#define H1 8
#define C1 32
#define D1 (H1*C1)               // 256
#define C2 32
#define C3 64

typedef unsigned short u16;
typedef unsigned int u32;

__device__ __forceinline__ float lrelu(float x) { return x >= 0.f ? x : 0.2f * x; }
__device__ __forceinline__ float eluf(float x)  { return x > 0.f ? x : (expf(x) - 1.f); }

__device__ __forceinline__ u16 f2bf(float f) {
    u32 u = __float_as_uint(f);
    return (u16)((u + 0x7FFFu + ((u >> 16) & 1u)) >> 16);   // RNE
}
__device__ __forceinline__ u32 pack2bf(float lo, float hi) {
    return ((u32)f2bf(hi) << 16) | (u32)f2bf(lo);
}
// uint2 = 4 consecutive bf16 -> float4
__device__ __forceinline__ float4 bf4_to_f4(uint2 v) {
    float4 r;
    r.x = __uint_as_float(v.x << 16);
    r.y = __uint_as_float(v.x & 0xFFFF0000u);
    r.z = __uint_as_float(v.y << 16);
    r.w = __uint_as_float(v.y & 0xFFFF0000u);
    return r;
}

// ---------------- CSR build ----------------

__global__ void hist_kernel(const int* __restrict__ dstArr, int* __restrict__ deg) {
    int e = blockIdx.x * 256 + threadIdx.x;
    if (e >= ET) return;
    int d = (e < N_EDGES) ? dstArr[e] : (e - N_EDGES);
    atomicAdd(&deg[d], 1);
}

__global__ __launch_bounds__(1024) void scan_kernel(const int* __restrict__ deg,
                                                    int* __restrict__ off,
                                                    int* __restrict__ cur, int n) {
    __shared__ int sdata[1024];
    int t = threadIdx.x;
    const int CH = 64;
    int base = t * CH;
    int sum = 0;
    for (int u = 0; u < CH; ++u) {
        int ix = base + u;
        sum += (ix < n) ? deg[ix] : 0;
    }
    sdata[t] = sum;
    __syncthreads();
    for (int o = 1; o < 1024; o <<= 1) {
        int x = (t >= o) ? sdata[t - o] : 0;
        __syncthreads();
        sdata[t] += x;
        __syncthreads();
    }
    int run = sdata[t] - sum;   // exclusive prefix
    for (int u = 0; u < CH; ++u) {
        int ix = base + u;
        if (ix < n) {
            off[ix] = run; cur[ix] = run;
            run += deg[ix];
        }
    }
    if (t == 1023) off[n] = sdata[1023];
}

__global__ void scatter_kernel(const int* __restrict__ srcArr, const int* __restrict__ dstArr,
                               int* __restrict__ cur, int* __restrict__ csr) {
    int e = blockIdx.x * 256 + threadIdx.x;
    if (e >= ET) return;
    int s, d;
    if (e < N_EDGES) { s = srcArr[e]; d = dstArr[e]; } else { s = d = e - N_EDGES; }
    int pos = atomicAdd(&cur[d], 1);
    csr[pos] = s;
}

// ---------------- templated f32 GEMM, optional bf16 output ----------------

template<int BM, int BN, int BK, int TM, int TN, typename OT>
__global__ __launch_bounds__(256) void gemm_t(const float* __restrict__ A,
                                              const float* __restrict__ B,
                                              OT* __restrict__ C,
                                              int M, int N, int K) {
    constexpr int TX = BN / TN;
    constexpr int TY = BM / TM;
    static_assert(TX * TY == 256, "thread grid");
    constexpr int LDA = BM + 4;
    __shared__ float As[BK][LDA];
    __shared__ float Bs[BK][BN];

    int tid = threadIdx.x;
    int bm = blockIdx.y * BM;
    int bn = blockIdx.x * BN;
    int tx = tid % TX;
    int ty = tid / TX;

    float acc[TM][TN] = {};

    constexpr int AF4 = BM * BK / 4;
    constexpr int FPR = BK / 4;
    constexpr int BF4 = BK * BN / 4;
    constexpr int BPR = BN / 4;

    for (int k0 = 0; k0 < K; k0 += BK) {
#pragma unroll
        for (int f = tid; f < AF4; f += 256) {
            int r = f / FPR, c4 = f % FPR;
            int gr = bm + r; if (gr > M - 1) gr = M - 1;
            float4 v = *(const float4*)(A + (size_t)gr * K + k0 + c4 * 4);
            As[c4 * 4 + 0][r] = v.x;
            As[c4 * 4 + 1][r] = v.y;
            As[c4 * 4 + 2][r] = v.z;
            As[c4 * 4 + 3][r] = v.w;
        }
#pragma unroll
        for (int f = tid; f < BF4; f += 256) {
            int kk = f / BPR, j4 = f % BPR;
            *(float4*)&Bs[kk][j4 * 4] = *(const float4*)(B + (size_t)(k0 + kk) * N + bn + j4 * 4);
        }
        __syncthreads();
#pragma unroll
        for (int kk = 0; kk < BK; ++kk) {
            float a[TM], b[TN];
#pragma unroll
            for (int i = 0; i < TM; i += 4)
                *(float4*)&a[i] = *(const float4*)&As[kk][ty * TM + i];
            if constexpr (TN == 8) {
                *(float4*)&b[0] = *(const float4*)&Bs[kk][tx * 4];
                *(float4*)&b[4] = *(const float4*)&Bs[kk][BN / 2 + tx * 4];
            } else if constexpr (TN == 4) {
                *(float4*)&b[0] = *(const float4*)&Bs[kk][tx * 4];
            } else {
                b[0] = Bs[kk][tx * 2];
                b[1] = Bs[kk][tx * 2 + 1];
            }
#pragma unroll
            for (int i = 0; i < TM; ++i)
#pragma unroll
                for (int jj = 0; jj < TN; ++jj)
                    acc[i][jj] += a[i] * b[jj];
        }
        __syncthreads();
    }
#pragma unroll
    for (int i = 0; i < TM; ++i) {
        int gr = bm + ty * TM + i;
        if (gr >= M) break;
        if constexpr (sizeof(OT) == 2) {
            // bf16 output
            if constexpr (TN == 8) {
                uint2 p0, p1;
                p0.x = pack2bf(acc[i][0], acc[i][1]);
                p0.y = pack2bf(acc[i][2], acc[i][3]);
                p1.x = pack2bf(acc[i][4], acc[i][5]);
                p1.y = pack2bf(acc[i][6], acc[i][7]);
                *(uint2*)((u16*)C + (size_t)gr * N + bn + tx * 4) = p0;
                *(uint2*)((u16*)C + (size_t)gr * N + bn + BN / 2 + tx * 4) = p1;
            } else if constexpr (TN == 4) {
                uint2 p0;
                p0.x = pack2bf(acc[i][0], acc[i][1]);
                p0.y = pack2bf(acc[i][2], acc[i][3]);
                *(uint2*)((u16*)C + (size_t)gr * N + bn + tx * 4) = p0;
            } else {
                u32 p = pack2bf(acc[i][0], acc[i][1]);
                *(u32*)((u16*)C + (size_t)gr * N + bn + tx * 2) = p;
            }
        } else {
            if constexpr (TN == 8) {
                *(float4*)((float*)C + (size_t)gr * N + bn + tx * 4) = *(float4*)&acc[i][0];
                *(float4*)((float*)C + (size_t)gr * N + bn + BN / 2 + tx * 4) = *(float4*)&acc[i][4];
            } else if constexpr (TN == 4) {
                *(float4*)((float*)C + (size_t)gr * N + bn + tx * 4) = *(float4*)&acc[i][0];
            } else {
                *(float2*)((float*)C + (size_t)gr * N + bn + tx * 2) = *(float2*)&acc[i][0];
            }
        }
    }
}

// ---------------- per-node attention coefficients (f32 h) ----------------

__global__ void alpha_kernel(const float* __restrict__ h, const float* __restrict__ a_src,
                             const float* __restrict__ a_dst, float* __restrict__ as,
                             float* __restrict__ ad, int n, int H, int C) {
    int t = blockIdx.x * 256 + threadIdx.x;
    if (t >= n * H) return;
    int hh = t % H;
    const float* hp  = h + (size_t)t * C;
    const float* asp = a_src + hh * C;
    const float* adp = a_dst + hh * C;
    float s1 = 0.f, s2 = 0.f;
    for (int c = 0; c < C; c += 4) {
        float4 hv = *(const float4*)(hp + c);
        float4 sv = *(const float4*)(asp + c);
        float4 dv = *(const float4*)(adp + c);
        s1 += hv.x * sv.x + hv.y * sv.y + hv.z * sv.z + hv.w * sv.w;
        s2 += hv.x * dv.x + hv.y * dv.y + hv.z * dv.z + hv.w * dv.w;
    }
    as[t] = s1;
    ad[t] = s2;
}

// ---------------- per-node attention coefficients (bf16 h, layer 1) ----------------

__global__ void alpha_bf16_kernel(const u16* __restrict__ h, const float* __restrict__ a_src,
                                  const float* __restrict__ a_dst, float* __restrict__ as,
                                  float* __restrict__ ad, int n, int H, int C) {
    int t = blockIdx.x * 256 + threadIdx.x;
    if (t >= n * H) return;
    int hh = t % H;
    const u16* hp    = h + (size_t)t * C;
    const float* asp = a_src + hh * C;
    const float* adp = a_dst + hh * C;
    float s1 = 0.f, s2 = 0.f;
    for (int c = 0; c < C; c += 4) {
        float4 hv = bf4_to_f4(*(const uint2*)(hp + c));
        float4 sv = *(const float4*)(asp + c);
        float4 dv = *(const float4*)(adp + c);
        s1 += hv.x * sv.x + hv.y * sv.y + hv.z * sv.z + hv.w * sv.w;
        s2 += hv.x * dv.x + hv.y * dv.y + hv.z * dv.z + hv.w * dv.w;
    }
    as[t] = s1;
    ad[t] = s2;
}

// ---------------- layer 1 aggregation: H=8, C=32, wave per node, bf16 h ----------------
// single pass, no max (|e| small, exp safe); unroll 4, direct csr reads.

__global__ __launch_bounds__(256) void agg1_kernel(const int* __restrict__ off, const int* __restrict__ csr,
                                                   const u16* __restrict__ h, const float* __restrict__ as,
                                                   const float* __restrict__ ad, const float* __restrict__ bias,
                                                   float* __restrict__ out) {
    int node = blockIdx.x * 4 + (threadIdx.x >> 6);
    if (node >= N_NODES) return;
    int lane = threadIdx.x & 63;
    int hh = lane >> 3;
    int j  = lane & 7;
    int s0 = off[node];
    int deg = off[node + 1] - s0;
    float adv = ad[node * H1 + hh];

    float4 acc = make_float4(0.f, 0.f, 0.f, 0.f);
    float dsum = 0.f;
    int i = 0;
    for (; i + 4 <= deg; i += 4) {
        int sa = csr[s0 + i];
        int sb = csr[s0 + i + 1];
        int sc = csr[s0 + i + 2];
        int sd = csr[s0 + i + 3];
        uint2 va = *(const uint2*)(h + (size_t)sa * D1 + hh * C1 + j * 4);
        uint2 vb = *(const uint2*)(h + (size_t)sb * D1 + hh * C1 + j * 4);
        uint2 vc = *(const uint2*)(h + (size_t)sc * D1 + hh * C1 + j * 4);
        uint2 vd = *(const uint2*)(h + (size_t)sd * D1 + hh * C1 + j * 4);
        float wa = __expf(lrelu(as[sa * H1 + hh] + adv));
        float wb = __expf(lrelu(as[sb * H1 + hh] + adv));
        float wc = __expf(lrelu(as[sc * H1 + hh] + adv));
        float wd = __expf(lrelu(as[sd * H1 + hh] + adv));
        float4 ha = bf4_to_f4(va);
        float4 hb = bf4_to_f4(vb);
        float4 hc = bf4_to_f4(vc);
        float4 hd = bf4_to_f4(vd);
        dsum += wa + wb + wc + wd;
        acc.x += wa * ha.x + wb * hb.x + wc * hc.x + wd * hd.x;
        acc.y += wa * ha.y + wb * hb.y + wc * hc.y + wd * hd.y;
        acc.z += wa * ha.z + wb * hb.z + wc * hc.z + wd * hd.z;
        acc.w += wa * ha.w + wb * hb.w + wc * hc.w + wd * hd.w;
    }
    for (; i < deg; ++i) {
        int s = csr[s0 + i];
        float4 hv = bf4_to_f4(*(const uint2*)(h + (size_t)s * D1 + hh * C1 + j * 4));
        float w = __expf(lrelu(as[s * H1 + hh] + adv));
        dsum += w;
        acc.x += w * hv.x; acc.y += w * hv.y; acc.z += w * hv.z; acc.w += w * hv.w;
    }
    float inv = 1.f / (dsum + 1e-16f);
    int ob = node * D1 + hh * C1 + j * 4;
    const float* bp = bias + hh * C1 + j * 4;
    float4 r;
    r.x = eluf(acc.x * inv + bp[0]);
    r.y = eluf(acc.y * inv + bp[1]);
    r.z = eluf(acc.z * inv + bp[2]);
    r.w = eluf(acc.w * inv + bp[3]);
    *(float4*)(out + ob) = r;
}

// ---------------- layer 2 aggregation: H=1, C=32, wave per node (f32 h) ----------------

__global__ __launch_bounds__(256) void agg32_kernel(const int* __restrict__ off, const int* __restrict__ csr,
                                                    const float* __restrict__ h, const float* __restrict__ as,
                                                    const float* __restrict__ ad, const float* __restrict__ bias,
                                                    float* __restrict__ out) {
    int node = blockIdx.x * 4 + (threadIdx.x >> 6);
    if (node >= N_NODES) return;
    int lane = threadIdx.x & 63;
    int c = lane & 31;
    int half = lane >> 5;
    int s0 = off[node];
    int deg = off[node + 1] - s0;
    float adv = ad[node];

    float acc = 0.f, dsum = 0.f;
    int i = half;
    for (; i + 6 < deg; i += 8) {
        int sa = csr[s0 + i];
        int sb = csr[s0 + i + 2];
        int sc = csr[s0 + i + 4];
        int sd = csr[s0 + i + 6];
        float ha = h[(size_t)sa * C2 + c];
        float hb = h[(size_t)sb * C2 + c];
        float hc = h[(size_t)sc * C2 + c];
        float hd = h[(size_t)sd * C2 + c];
        float wa = __expf(lrelu(as[sa] + adv));
        float wb = __expf(lrelu(as[sb] + adv));
        float wc = __expf(lrelu(as[sc] + adv));
        float wd = __expf(lrelu(as[sd] + adv));
        dsum += wa + wb + wc + wd;
        acc += wa * ha + wb * hb + wc * hc + wd * hd;
    }
    for (; i < deg; i += 2) {
        int s = csr[s0 + i];
        float w = __expf(lrelu(as[s] + adv));
        dsum += w;
        acc += w * h[(size_t)s * C2 + c];
    }
    acc  += __shfl_xor(acc, 32);
    dsum += __shfl_xor(dsum, 32);
    if (half == 0) {
        out[(size_t)node * C2 + c] = eluf(acc / (dsum + 1e-16f) + bias[c]);
    }
}

// ---------------- layer 3 aggregation: H=1, C=64, wave per node, no ELU (f32 h) ----------------

__global__ __launch_bounds__(256) void agg64_kernel(const int* __restrict__ off, const int* __restrict__ csr,
                                                    const float* __restrict__ h, const float* __restrict__ as,
                                                    const float* __restrict__ ad, const float* __restrict__ bias,
                                                    float* __restrict__ out) {
    int node = blockIdx.x * 4 + (threadIdx.x >> 6);
    if (node >= N_NODES) return;
    int lane = threadIdx.x & 63;
    int s0 = off[node];
    int deg = off[node + 1] - s0;
    float adv = ad[node];

    float acc = 0.f, dsum = 0.f;
    int i = 0;
    for (; i + 4 <= deg; i += 4) {
        int sa = csr[s0 + i];
        int sb = csr[s0 + i + 1];
        int sc = csr[s0 + i + 2];
        int sd = csr[s0 + i + 3];
        float ha = h[(size_t)sa * C3 + lane];
        float hb = h[(size_t)sb * C3 + lane];
        float hc = h[(size_t)sc * C3 + lane];
        float hd = h[(size_t)sd * C3 + lane];
        float wa = __expf(lrelu(as[sa] + adv));
        float wb = __expf(lrelu(as[sb] + adv));
        float wc = __expf(lrelu(as[sc] + adv));
        float wd = __expf(lrelu(as[sd] + adv));
        dsum += wa + wb + wc + wd;
        acc += wa * ha + wb * hb + wc * hc + wd * hd;
    }
    for (; i < deg; ++i) {
        int s = csr[s0 + i];
        float w = __expf(lrelu(as[s] + adv));
        dsum += w;
        acc += w * h[(size_t)s * C3 + lane];
    }
    out[(size_t)node * C3 + lane] = acc / (dsum + 1e-16f) + bias[lane];
}

// ---------------- launch ----------------

extern "C" void kernel_launch(void* const* d_in, const int* in_sizes, int n_in,
                              void* d_out, int out_size, void* d_ws, size_t ws_size,
                              hipStream_t stream) {
    const float* x   = (const float*)d_in[0];
    const int*   ei  = (const int*)d_in[1];
    const float* W1  = (const float*)d_in[2];
    const float* aS1 = (const float*)d_in[3];
    const float* aD1 = (const float*)d_in[4];
    const float* b1  = (const float*)d_in[5];
    const float* W2  = (const float*)d_in[6];
    const float* aS2 = (const float*)d_in[7];
    const float* aD2 = (const float*)d_in[8];
    const float* b2  = (const float*)d_in[9];
    const float* W3  = (const float*)d_in[10];
    const float* aS3 = (const float*)d_in[11];
    const float* aD3 = (const float*)d_in[12];
    const float* b3  = (const float*)d_in[13];
    float* out = (float*)d_out;

    char* p = (char*)d_ws;
    auto alloc = [&](size_t bytes) -> void* {
        void* r = (void*)p;
        p += (bytes + 255) & ~(size_t)255;
        return r;
    };
    u16*   h1b  = (u16*)alloc((size_t)N_NODES * D1 * 2);     // layer-1 features, bf16 (25.6 MB)
    float* bufB = (float*)alloc((size_t)N_NODES * D1 * 4);   // layer-1 aggregated out, f32 (51.2 MB)
    float* bufA = (float*)alloc((size_t)N_NODES * C3 * 4);   // gemm2/gemm3 outputs (12.8 MB)
    int*   deg  = (int*)alloc((size_t)N_NODES * 4);
    int*   off  = (int*)alloc((size_t)(N_NODES + 1) * 4);
    int*   cur  = (int*)alloc((size_t)N_NODES * 4);
    int*   csr  = (int*)alloc((size_t)ET * 4);
    float* asb  = (float*)alloc((size_t)N_NODES * H1 * 4);
    float* adb  = (float*)alloc((size_t)N_NODES * H1 * 4);

    const int* srcArr = ei;
    const int* dstArr = ei + N_EDGES;

    // --- CSR build ---
    hipMemsetAsync(deg, 0, (size_t)N_NODES * 4, stream);
    int eb = (ET + 255) / 256;
    hist_kernel<<<eb, 256, 0, stream>>>(dstArr, deg);
    scan_kernel<<<1, 1024, 0, stream>>>(deg, off, cur, N_NODES);
    scatter_kernel<<<eb, 256, 0, stream>>>(srcArr, dstArr, cur, csr);

    int nb4 = (N_NODES + 3) / 4;

    // --- layer 1: gemm -> bf16 h1 ---
    gemm_t<128, 128, 16, 8, 8, u16><<<dim3(D1 / 128, (N_NODES + 127) / 128), 256, 0, stream>>>(x, W1, h1b, N_NODES, D1, F0);
    alpha_bf16_kernel<<<(N_NODES * H1 + 255) / 256, 256, 0, stream>>>(h1b, aS1, aD1, asb, adb, N_NODES, H1, C1);
    agg1_kernel<<<nb4, 256, 0, stream>>>(off, csr, h1b, asb, adb, b1, bufB);

    // --- layer 2 ---
    gemm_t<64, 32, 32, 4, 2, float><<<dim3(1, (N_NODES + 63) / 64), 256, 0, stream>>>(bufB, W2, bufA, N_NODES, C2, D1);
    alpha_kernel<<<(N_NODES + 255) / 256, 256, 0, stream>>>(bufA, aS2, aD2, asb, adb, N_NODES, 1, C2);
    agg32_kernel<<<nb4, 256, 0, stream>>>(off, csr, bufA, asb, adb, b2, bufB);

    // --- layer 3 ---
    gemm_t<64, 64, 32, 4, 4, float><<<dim3(1, (N_NODES + 63) / 64), 256, 0, stream>>>(bufB, W3, bufA, N_NODES, C3, C2);
    alpha_kernel<<<(N_NODES + 255) / 256, 256, 0, stream>>>(bufA, aS3, aD3, asb, adb, N_NODES, 1, C3);
    agg64_kernel<<<nb4, 256, 0, stream>>>(off, csr, bufA, asb, adb, b3, out);
}

// Round 8
// 449.853 us; speedup vs baseline: 1.5036x; 1.2537x over previous
//
#include <hip/hip_runtime.h>
#include <hip/hip_bf16.h>
#include <math.h>

#define N_NODES 50000
#define N_EDGES 800000
#define ET (N_EDGES + N_NODES)   // with self loops = 850000
#define F0 128
#define H1 8
#define C1 32
#define D1 (H1*C1)               // 256
#define C2 32
#define C3 64

#define SCAN_NB 64                // blocks in multi-block scan
#define SCAN_CH 4                 // elements per thread (64*256*4 = 65536 >= 50000)

typedef unsigned short u16;
typedef unsigned int u32;

__device__ __forceinline__ float lrelu(float x) { return x >= 0.f ? x : 0.2f * x; }
__device__ __forceinline__ float eluf(float x)  { return x > 0.f ? x : (expf(x) - 1.f); }

__device__ __forceinline__ u16 f2bf(float f) {
    u32 u = __float_as_uint(f);
    return (u16)((u + 0x7FFFu + ((u >> 16) & 1u)) >> 16);   // RNE
}
__device__ __forceinline__ u32 pack2bf(float lo, float hi) {
    return ((u32)f2bf(hi) << 16) | (u32)f2bf(lo);
}
__device__ __forceinline__ float4 bf4_to_f4(uint2 v) {
    float4 r;
    r.x = __uint_as_float(v.x << 16);
    r.y = __uint_as_float(v.x & 0xFFFF0000u);
    r.z = __uint_as_float(v.y << 16);
    r.w = __uint_as_float(v.y & 0xFFFF0000u);
    return r;
}

// ---------------- CSR build ----------------

__global__ void hist_kernel(const int* __restrict__ dstArr, int* __restrict__ deg) {
    int e = blockIdx.x * 256 + threadIdx.x;
    if (e >= ET) return;
    int d = (e < N_EDGES) ? dstArr[e] : (e - N_EDGES);
    atomicAdd(&deg[d], 1);
}

// phase 1: per-block totals
__global__ __launch_bounds__(256) void partial_kernel(const int* __restrict__ deg,
                                                      int* __restrict__ bsum, int n) {
    __shared__ int sdata[256];
    int t = threadIdx.x;
    int base = (blockIdx.x * 256 + t) * SCAN_CH;
    int s = 0;
#pragma unroll
    for (int u = 0; u < SCAN_CH; ++u) {
        int ix = base + u;
        s += (ix < n) ? deg[ix] : 0;
    }
    sdata[t] = s;
    __syncthreads();
    for (int o = 128; o > 0; o >>= 1) {
        if (t < o) sdata[t] += sdata[t + o];
        __syncthreads();
    }
    if (t == 0) bsum[blockIdx.x] = sdata[0];
}

// phase 2: one wave scans the SCAN_NB block sums (exclusive)
__global__ __launch_bounds__(64) void bscan_kernel(const int* __restrict__ bsum,
                                                   int* __restrict__ bbase,
                                                   int* __restrict__ off, int n) {
    int t = threadIdx.x;
    int v = (t < SCAN_NB) ? bsum[t] : 0;
    int orig = v;
#pragma unroll
    for (int o = 1; o < 64; o <<= 1) {
        int x = __shfl_up(v, o);
        if (t >= o) v += x;
    }
    if (t < SCAN_NB) bbase[t] = v - orig;   // exclusive
    if (t == 0) off[n] = ET;                // total is statically known
}

// phase 3: per-block local scan + base, write off/cur
__global__ __launch_bounds__(256) void finish_kernel(const int* __restrict__ deg,
                                                     const int* __restrict__ bbase,
                                                     int* __restrict__ off,
                                                     int* __restrict__ cur, int n) {
    __shared__ int sdata[256];
    int t = threadIdx.x;
    int base = (blockIdx.x * 256 + t) * SCAN_CH;
    int d[SCAN_CH];
    int s = 0;
#pragma unroll
    for (int u = 0; u < SCAN_CH; ++u) {
        int ix = base + u;
        d[u] = (ix < n) ? deg[ix] : 0;
        s += d[u];
    }
    sdata[t] = s;
    __syncthreads();
    for (int o = 1; o < 256; o <<= 1) {
        int x = (t >= o) ? sdata[t - o] : 0;
        __syncthreads();
        sdata[t] += x;
        __syncthreads();
    }
    int run = bbase[blockIdx.x] + sdata[t] - s;   // exclusive prefix for this thread
#pragma unroll
    for (int u = 0; u < SCAN_CH; ++u) {
        int ix = base + u;
        if (ix < n) {
            off[ix] = run; cur[ix] = run;
            run += d[u];
        }
    }
}

__global__ void scatter_kernel(const int* __restrict__ srcArr, const int* __restrict__ dstArr,
                               int* __restrict__ cur, int* __restrict__ csr) {
    int e = blockIdx.x * 256 + threadIdx.x;
    if (e >= ET) return;
    int s, d;
    if (e < N_EDGES) { s = srcArr[e]; d = dstArr[e]; } else { s = d = e - N_EDGES; }
    int pos = atomicAdd(&cur[d], 1);
    csr[pos] = s;
}

// ---------------- templated f32 GEMM, optional bf16 output ----------------

template<int BM, int BN, int BK, int TM, int TN, typename OT>
__global__ __launch_bounds__(256) void gemm_t(const float* __restrict__ A,
                                              const float* __restrict__ B,
                                              OT* __restrict__ C,
                                              int M, int N, int K) {
    constexpr int TX = BN / TN;
    constexpr int TY = BM / TM;
    static_assert(TX * TY == 256, "thread grid");
    constexpr int LDA = BM + 4;
    __shared__ float As[BK][LDA];
    __shared__ float Bs[BK][BN];

    int tid = threadIdx.x;
    int bm = blockIdx.y * BM;
    int bn = blockIdx.x * BN;
    int tx = tid % TX;
    int ty = tid / TX;

    float acc[TM][TN] = {};

    constexpr int AF4 = BM * BK / 4;
    constexpr int FPR = BK / 4;
    constexpr int BF4 = BK * BN / 4;
    constexpr int BPR = BN / 4;

    for (int k0 = 0; k0 < K; k0 += BK) {
#pragma unroll
        for (int f = tid; f < AF4; f += 256) {
            int r = f / FPR, c4 = f % FPR;
            int gr = bm + r; if (gr > M - 1) gr = M - 1;
            float4 v = *(const float4*)(A + (size_t)gr * K + k0 + c4 * 4);
            As[c4 * 4 + 0][r] = v.x;
            As[c4 * 4 + 1][r] = v.y;
            As[c4 * 4 + 2][r] = v.z;
            As[c4 * 4 + 3][r] = v.w;
        }
#pragma unroll
        for (int f = tid; f < BF4; f += 256) {
            int kk = f / BPR, j4 = f % BPR;
            *(float4*)&Bs[kk][j4 * 4] = *(const float4*)(B + (size_t)(k0 + kk) * N + bn + j4 * 4);
        }
        __syncthreads();
#pragma unroll
        for (int kk = 0; kk < BK; ++kk) {
            float a[TM], b[TN];
#pragma unroll
            for (int i = 0; i < TM; i += 4)
                *(float4*)&a[i] = *(const float4*)&As[kk][ty * TM + i];
            if constexpr (TN == 8) {
                *(float4*)&b[0] = *(const float4*)&Bs[kk][tx * 4];
                *(float4*)&b[4] = *(const float4*)&Bs[kk][BN / 2 + tx * 4];
            } else if constexpr (TN == 4) {
                *(float4*)&b[0] = *(const float4*)&Bs[kk][tx * 4];
            } else {
                b[0] = Bs[kk][tx * 2];
                b[1] = Bs[kk][tx * 2 + 1];
            }
#pragma unroll
            for (int i = 0; i < TM; ++i)
#pragma unroll
                for (int jj = 0; jj < TN; ++jj)
                    acc[i][jj] += a[i] * b[jj];
        }
        __syncthreads();
    }
#pragma unroll
    for (int i = 0; i < TM; ++i) {
        int gr = bm + ty * TM + i;
        if (gr >= M) break;
        if constexpr (sizeof(OT) == 2) {
            if constexpr (TN == 8) {
                uint2 p0, p1;
                p0.x = pack2bf(acc[i][0], acc[i][1]);
                p0.y = pack2bf(acc[i][2], acc[i][3]);
                p1.x = pack2bf(acc[i][4], acc[i][5]);
                p1.y = pack2bf(acc[i][6], acc[i][7]);
                *(uint2*)((u16*)C + (size_t)gr * N + bn + tx * 4) = p0;
                *(uint2*)((u16*)C + (size_t)gr * N + bn + BN / 2 + tx * 4) = p1;
            } else if constexpr (TN == 4) {
                uint2 p0;
                p0.x = pack2bf(acc[i][0], acc[i][1]);
                p0.y = pack2bf(acc[i][2], acc[i][3]);
                *(uint2*)((u16*)C + (size_t)gr * N + bn + tx * 4) = p0;
            } else {
                u32 p = pack2bf(acc[i][0], acc[i][1]);
                *(u32*)((u16*)C + (size_t)gr * N + bn + tx * 2) = p;
            }
        } else {
            if constexpr (TN == 8) {
                *(float4*)((float*)C + (size_t)gr * N + bn + tx * 4) = *(float4*)&acc[i][0];
                *(float4*)((float*)C + (size_t)gr * N + bn + BN / 2 + tx * 4) = *(float4*)&acc[i][4];
            } else if constexpr (TN == 4) {
                *(float4*)((float*)C + (size_t)gr * N + bn + tx * 4) = *(float4*)&acc[i][0];
            } else {
                *(float2*)((float*)C + (size_t)gr * N + bn + tx * 2) = *(float2*)&acc[i][0];
            }
        }
    }
}

// ---------------- per-node attention coefficients (f32 h) ----------------

__global__ void alpha_kernel(const float* __restrict__ h, const float* __restrict__ a_src,
                             const float* __restrict__ a_dst, float* __restrict__ as,
                             float* __restrict__ ad, int n, int H, int C) {
    int t = blockIdx.x * 256 + threadIdx.x;
    if (t >= n * H) return;
    int hh = t % H;
    const float* hp  = h + (size_t)t * C;
    const float* asp = a_src + hh * C;
    const float* adp = a_dst + hh * C;
    float s1 = 0.f, s2 = 0.f;
    for (int c = 0; c < C; c += 4) {
        float4 hv = *(const float4*)(hp + c);
        float4 sv = *(const float4*)(asp + c);
        float4 dv = *(const float4*)(adp + c);
        s1 += hv.x * sv.x + hv.y * sv.y + hv.z * sv.z + hv.w * sv.w;
        s2 += hv.x * dv.x + hv.y * dv.y + hv.z * dv.z + hv.w * dv.w;
    }
    as[t] = s1;
    ad[t] = s2;
}

// ---------------- per-node attention coefficients (bf16 h, layer 1) ----------------

__global__ void alpha_bf16_kernel(const u16* __restrict__ h, const float* __restrict__ a_src,
                                  const float* __restrict__ a_dst, float* __restrict__ as,
                                  float* __restrict__ ad, int n, int H, int C) {
    int t = blockIdx.x * 256 + threadIdx.x;
    if (t >= n * H) return;
    int hh = t % H;
    const u16* hp    = h + (size_t)t * C;
    const float* asp = a_src + hh * C;
    const float* adp = a_dst + hh * C;
    float s1 = 0.f, s2 = 0.f;
    for (int c = 0; c < C; c += 4) {
        float4 hv = bf4_to_f4(*(const uint2*)(hp + c));
        float4 sv = *(const float4*)(asp + c);
        float4 dv = *(const float4*)(adp + c);
        s1 += hv.x * sv.x + hv.y * sv.y + hv.z * sv.z + hv.w * sv.w;
        s2 += hv.x * dv.x + hv.y * dv.y + hv.z * dv.z + hv.w * dv.w;
    }
    as[t] = s1;
    ad[t] = s2;
}

// ---------------- layer 1 aggregation: H=8, C=32, wave per node, bf16 h ----------------

__global__ __launch_bounds__(256) void agg1_kernel(const int* __restrict__ off, const int* __restrict__ csr,
                                                   const u16* __restrict__ h, const float* __restrict__ as,
                                                   const float* __restrict__ ad, const float* __restrict__ bias,
                                                   float* __restrict__ out) {
    int node = blockIdx.x * 4 + (threadIdx.x >> 6);
    if (node >= N_NODES) return;
    int lane = threadIdx.x & 63;
    int hh = lane >> 3;
    int j  = lane & 7;
    int s0 = off[node];
    int deg = off[node + 1] - s0;
    float adv = ad[node * H1 + hh];

    float4 acc = make_float4(0.f, 0.f, 0.f, 0.f);
    float dsum = 0.f;
    int i = 0;
    for (; i + 4 <= deg; i += 4) {
        int sa = csr[s0 + i];
        int sb = csr[s0 + i + 1];
        int sc = csr[s0 + i + 2];
        int sd = csr[s0 + i + 3];
        uint2 va = *(const uint2*)(h + (size_t)sa * D1 + hh * C1 + j * 4);
        uint2 vb = *(const uint2*)(h + (size_t)sb * D1 + hh * C1 + j * 4);
        uint2 vc = *(const uint2*)(h + (size_t)sc * D1 + hh * C1 + j * 4);
        uint2 vd = *(const uint2*)(h + (size_t)sd * D1 + hh * C1 + j * 4);
        float wa = __expf(lrelu(as[sa * H1 + hh] + adv));
        float wb = __expf(lrelu(as[sb * H1 + hh] + adv));
        float wc = __expf(lrelu(as[sc * H1 + hh] + adv));
        float wd = __expf(lrelu(as[sd * H1 + hh] + adv));
        float4 ha = bf4_to_f4(va);
        float4 hb = bf4_to_f4(vb);
        float4 hc = bf4_to_f4(vc);
        float4 hd = bf4_to_f4(vd);
        dsum += wa + wb + wc + wd;
        acc.x += wa * ha.x + wb * hb.x + wc * hc.x + wd * hd.x;
        acc.y += wa * ha.y + wb * hb.y + wc * hc.y + wd * hd.y;
        acc.z += wa * ha.z + wb * hb.z + wc * hc.z + wd * hd.z;
        acc.w += wa * ha.w + wb * hb.w + wc * hc.w + wd * hd.w;
    }
    for (; i < deg; ++i) {
        int s = csr[s0 + i];
        float4 hv = bf4_to_f4(*(const uint2*)(h + (size_t)s * D1 + hh * C1 + j * 4));
        float w = __expf(lrelu(as[s * H1 + hh] + adv));
        dsum += w;
        acc.x += w * hv.x; acc.y += w * hv.y; acc.z += w * hv.z; acc.w += w * hv.w;
    }
    float inv = 1.f / (dsum + 1e-16f);
    int ob = node * D1 + hh * C1 + j * 4;
    const float* bp = bias + hh * C1 + j * 4;
    float4 r;
    r.x = eluf(acc.x * inv + bp[0]);
    r.y = eluf(acc.y * inv + bp[1]);
    r.z = eluf(acc.z * inv + bp[2]);
    r.w = eluf(acc.w * inv + bp[3]);
    *(float4*)(out + ob) = r;
}

// ---------------- layer 2 aggregation: H=1, C=32, wave per node (f32 h) ----------------

__global__ __launch_bounds__(256) void agg32_kernel(const int* __restrict__ off, const int* __restrict__ csr,
                                                    const float* __restrict__ h, const float* __restrict__ as,
                                                    const float* __restrict__ ad, const float* __restrict__ bias,
                                                    float* __restrict__ out) {
    int node = blockIdx.x * 4 + (threadIdx.x >> 6);
    if (node >= N_NODES) return;
    int lane = threadIdx.x & 63;
    int c = lane & 31;
    int half = lane >> 5;
    int s0 = off[node];
    int deg = off[node + 1] - s0;
    float adv = ad[node];

    float acc = 0.f, dsum = 0.f;
    int i = half;
    for (; i + 6 < deg; i += 8) {
        int sa = csr[s0 + i];
        int sb = csr[s0 + i + 2];
        int sc = csr[s0 + i + 4];
        int sd = csr[s0 + i + 6];
        float ha = h[(size_t)sa * C2 + c];
        float hb = h[(size_t)sb * C2 + c];
        float hc = h[(size_t)sc * C2 + c];
        float hd = h[(size_t)sd * C2 + c];
        float wa = __expf(lrelu(as[sa] + adv));
        float wb = __expf(lrelu(as[sb] + adv));
        float wc = __expf(lrelu(as[sc] + adv));
        float wd = __expf(lrelu(as[sd] + adv));
        dsum += wa + wb + wc + wd;
        acc += wa * ha + wb * hb + wc * hc + wd * hd;
    }
    for (; i < deg; i += 2) {
        int s = csr[s0 + i];
        float w = __expf(lrelu(as[s] + adv));
        dsum += w;
        acc += w * h[(size_t)s * C2 + c];
    }
    acc  += __shfl_xor(acc, 32);
    dsum += __shfl_xor(dsum, 32);
    if (half == 0) {
        out[(size_t)node * C2 + c] = eluf(acc / (dsum + 1e-16f) + bias[c]);
    }
}

// ---------------- layer 3 aggregation: H=1, C=64, wave per node, no ELU (f32 h) ----------------

__global__ __launch_bounds__(256) void agg64_kernel(const int* __restrict__ off, const int* __restrict__ csr,
                                                    const float* __restrict__ h, const float* __restrict__ as,
                                                    const float* __restrict__ ad, const float* __restrict__ bias,
                                                    float* __restrict__ out) {
    int node = blockIdx.x * 4 + (threadIdx.x >> 6);
    if (node >= N_NODES) return;
    int lane = threadIdx.x & 63;
    int s0 = off[node];
    int deg = off[node + 1] - s0;
    float adv = ad[node];

    float acc = 0.f, dsum = 0.f;
    int i = 0;
    for (; i + 4 <= deg; i += 4) {
        int sa = csr[s0 + i];
        int sb = csr[s0 + i + 1];
        int sc = csr[s0 + i + 2];
        int sd = csr[s0 + i + 3];
        float ha = h[(size_t)sa * C3 + lane];
        float hb = h[(size_t)sb * C3 + lane];
        float hc = h[(size_t)sc * C3 + lane];
        float hd = h[(size_t)sd * C3 + lane];
        float wa = __expf(lrelu(as[sa] + adv));
        float wb = __expf(lrelu(as[sb] + adv));
        float wc = __expf(lrelu(as[sc] + adv));
        float wd = __expf(lrelu(as[sd] + adv));
        dsum += wa + wb + wc + wd;
        acc += wa * ha + wb * hb + wc * hc + wd * hd;
    }
    for (; i < deg; ++i) {
        int s = csr[s0 + i];
        float w = __expf(lrelu(as[s] + adv));
        dsum += w;
        acc += w * h[(size_t)s * C3 + lane];
    }
    out[(size_t)node * C3 + lane] = acc / (dsum + 1e-16f) + bias[lane];
}

// ---------------- launch ----------------

extern "C" void kernel_launch(void* const* d_in, const int* in_sizes, int n_in,
                              void* d_out, int out_size, void* d_ws, size_t ws_size,
                              hipStream_t stream) {
    const float* x   = (const float*)d_in[0];
    const int*   ei  = (const int*)d_in[1];
    const float* W1  = (const float*)d_in[2];
    const float* aS1 = (const float*)d_in[3];
    const float* aD1 = (const float*)d_in[4];
    const float* b1  = (const float*)d_in[5];
    const float* W2  = (const float*)d_in[6];
    const float* aS2 = (const float*)d_in[7];
    const float* aD2 = (const float*)d_in[8];
    const float* b2  = (const float*)d_in[9];
    const float* W3  = (const float*)d_in[10];
    const float* aS3 = (const float*)d_in[11];
    const float* aD3 = (const float*)d_in[12];
    const float* b3  = (const float*)d_in[13];
    float* out = (float*)d_out;

    char* p = (char*)d_ws;
    auto alloc = [&](size_t bytes) -> void* {
        void* r = (void*)p;
        p += (bytes + 255) & ~(size_t)255;
        return r;
    };
    u16*   h1b  = (u16*)alloc((size_t)N_NODES * D1 * 2);     // layer-1 features, bf16
    float* bufB = (float*)alloc((size_t)N_NODES * D1 * 4);   // layer-1 aggregated out, f32
    float* bufA = (float*)alloc((size_t)N_NODES * C3 * 4);   // gemm2/gemm3 outputs
    int*   deg  = (int*)alloc((size_t)N_NODES * 4);
    int*   off  = (int*)alloc((size_t)(N_NODES + 1) * 4);
    int*   cur  = (int*)alloc((size_t)N_NODES * 4);
    int*   csr  = (int*)alloc((size_t)ET * 4);
    float* asb  = (float*)alloc((size_t)N_NODES * H1 * 4);
    float* adb  = (float*)alloc((size_t)N_NODES * H1 * 4);
    int*   bsum = (int*)alloc((size_t)SCAN_NB * 4);
    int*   bbase= (int*)alloc((size_t)SCAN_NB * 4);

    const int* srcArr = ei;
    const int* dstArr = ei + N_EDGES;

    // --- CSR build ---
    hipMemsetAsync(deg, 0, (size_t)N_NODES * 4, stream);
    int eb = (ET + 255) / 256;
    hist_kernel<<<eb, 256, 0, stream>>>(dstArr, deg);
    partial_kernel<<<SCAN_NB, 256, 0, stream>>>(deg, bsum, N_NODES);
    bscan_kernel<<<1, 64, 0, stream>>>(bsum, bbase, off, N_NODES);
    finish_kernel<<<SCAN_NB, 256, 0, stream>>>(deg, bbase, off, cur, N_NODES);
    scatter_kernel<<<eb, 256, 0, stream>>>(srcArr, dstArr, cur, csr);

    int nb4 = (N_NODES + 3) / 4;

    // --- layer 1: gemm -> bf16 h1 ---
    gemm_t<128, 128, 16, 8, 8, u16><<<dim3(D1 / 128, (N_NODES + 127) / 128), 256, 0, stream>>>(x, W1, h1b, N_NODES, D1, F0);
    alpha_bf16_kernel<<<(N_NODES * H1 + 255) / 256, 256, 0, stream>>>(h1b, aS1, aD1, asb, adb, N_NODES, H1, C1);
    agg1_kernel<<<nb4, 256, 0, stream>>>(off, csr, h1b, asb, adb, b1, bufB);

    // --- layer 2 ---
    gemm_t<64, 32, 32, 4, 2, float><<<dim3(1, (N_NODES + 63) / 64), 256, 0, stream>>>(bufB, W2, bufA, N_NODES, C2, D1);
    alpha_kernel<<<(N_NODES + 255) / 256, 256, 0, stream>>>(bufA, aS2, aD2, asb, adb, N_NODES, 1, C2);
    agg32_kernel<<<nb4, 256, 0, stream>>>(off, csr, bufA, asb, adb, b2, bufB);

    // --- layer 3 ---
    gemm_t<64, 64, 32, 4, 4, float><<<dim3(1, (N_NODES + 63) / 64), 256, 0, stream>>>(bufB, W3, bufA, N_NODES, C3, C2);
    alpha_kernel<<<(N_NODES + 255) / 256, 256, 0, stream>>>(bufA, aS3, aD3, asb, adb, N_NODES, 1, C3);
    agg64_kernel<<<nb4, 256, 0, stream>>>(off, csr, bufA, asb, adb, b3, out);
}

// Round 9
// 410.467 us; speedup vs baseline: 1.6479x; 1.0960x over previous
//
#include <hip/hip_runtime.h>
#include <hip/hip_bf16.h>
#include <math.h>

#define N_NODES 50000
#define N_EDGES 800000
#define ET (N_EDGES + N_NODES)   // with self loops = 850000
#define F0 128
#define H1 8
#define C1 32
#define D1 (H1*C1)               // 256
#define C2 32
#define C3 64

#define SCAN_NB 64
#define SCAN_CH 4

typedef unsigned short u16;
typedef unsigned int u32;
typedef __attribute__((ext_vector_type(8))) short short8;
typedef __attribute__((ext_vector_type(4))) float f32x4;

__device__ __forceinline__ float lrelu(float x) { return x >= 0.f ? x : 0.2f * x; }
__device__ __forceinline__ float eluf(float x)  { return x > 0.f ? x : (expf(x) - 1.f); }

__device__ __forceinline__ u16 f2bf(float f) {
    u32 u = __float_as_uint(f);
    return (u16)((u + 0x7FFFu + ((u >> 16) & 1u)) >> 16);   // RNE
}
__device__ __forceinline__ u32 pack2bf(float lo, float hi) {
    return ((u32)f2bf(hi) << 16) | (u32)f2bf(lo);
}
__device__ __forceinline__ float bf2f(u16 v) {
    return __uint_as_float((u32)v << 16);
}
__device__ __forceinline__ float4 bf4_to_f4(uint2 v) {
    float4 r;
    r.x = __uint_as_float(v.x << 16);
    r.y = __uint_as_float(v.x & 0xFFFF0000u);
    r.z = __uint_as_float(v.y << 16);
    r.w = __uint_as_float(v.y & 0xFFFF0000u);
    return r;
}

// ---------------- CSR build ----------------

__global__ void hist_kernel(const int* __restrict__ dstArr, int* __restrict__ deg) {
    int e = blockIdx.x * 256 + threadIdx.x;
    if (e >= ET) return;
    int d = (e < N_EDGES) ? dstArr[e] : (e - N_EDGES);
    atomicAdd(&deg[d], 1);
}

__global__ __launch_bounds__(256) void partial_kernel(const int* __restrict__ deg,
                                                      int* __restrict__ bsum, int n) {
    __shared__ int sdata[256];
    int t = threadIdx.x;
    int base = (blockIdx.x * 256 + t) * SCAN_CH;
    int s = 0;
#pragma unroll
    for (int u = 0; u < SCAN_CH; ++u) {
        int ix = base + u;
        s += (ix < n) ? deg[ix] : 0;
    }
    sdata[t] = s;
    __syncthreads();
    for (int o = 128; o > 0; o >>= 1) {
        if (t < o) sdata[t] += sdata[t + o];
        __syncthreads();
    }
    if (t == 0) bsum[blockIdx.x] = sdata[0];
}

__global__ __launch_bounds__(64) void bscan_kernel(const int* __restrict__ bsum,
                                                   int* __restrict__ bbase,
                                                   int* __restrict__ off, int n) {
    int t = threadIdx.x;
    int v = (t < SCAN_NB) ? bsum[t] : 0;
    int orig = v;
#pragma unroll
    for (int o = 1; o < 64; o <<= 1) {
        int x = __shfl_up(v, o);
        if (t >= o) v += x;
    }
    if (t < SCAN_NB) bbase[t] = v - orig;
    if (t == 0) off[n] = ET;
}

__global__ __launch_bounds__(256) void finish_kernel(const int* __restrict__ deg,
                                                     const int* __restrict__ bbase,
                                                     int* __restrict__ off,
                                                     int* __restrict__ cur, int n) {
    __shared__ int sdata[256];
    int t = threadIdx.x;
    int base = (blockIdx.x * 256 + t) * SCAN_CH;
    int d[SCAN_CH];
    int s = 0;
#pragma unroll
    for (int u = 0; u < SCAN_CH; ++u) {
        int ix = base + u;
        d[u] = (ix < n) ? deg[ix] : 0;
        s += d[u];
    }
    sdata[t] = s;
    __syncthreads();
    for (int o = 1; o < 256; o <<= 1) {
        int x = (t >= o) ? sdata[t - o] : 0;
        __syncthreads();
        sdata[t] += x;
        __syncthreads();
    }
    int run = bbase[blockIdx.x] + sdata[t] - s;
#pragma unroll
    for (int u = 0; u < SCAN_CH; ++u) {
        int ix = base + u;
        if (ix < n) {
            off[ix] = run; cur[ix] = run;
            run += d[u];
        }
    }
}

__global__ void scatter_kernel(const int* __restrict__ srcArr, const int* __restrict__ dstArr,
                               int* __restrict__ cur, int* __restrict__ csr) {
    int e = blockIdx.x * 256 + threadIdx.x;
    if (e >= ET) return;
    int s, d;
    if (e < N_EDGES) { s = srcArr[e]; d = dstArr[e]; } else { s = d = e - N_EDGES; }
    int pos = atomicAdd(&cur[d], 1);
    csr[pos] = s;
}

// ---------------- gemm1: x[M,128] @ W1[128,256] -> bf16, MFMA 16x16x32 ----------------
// Block: 256 thr = 4 waves; block tile 64 rows x 64 cols; wave = 16 rows x 64 cols.
// W1 block-column staged in LDS transposed [n][k] bf16, stride 136 (16B-aligned rows).
// Layouts (HW-verified, cdna docs): A[m=lane&15][k=(lane>>4)*8+j];
// B[n=lane&15][k=(lane>>4)*8+j]; C/D col=lane&15, row=(lane>>4)*4+reg.

#define WKS 136   // LDS k-stride in u16 elems (272 B, 16B multiple)

__global__ __launch_bounds__(256) void gemm1_mfma(const float* __restrict__ x,
                                                  const float* __restrict__ W1,
                                                  u16* __restrict__ h1b, int M) {
    __shared__ u16 Wt[64][WKS];
    int tid = threadIdx.x;
    int bm = blockIdx.y * 64;
    int bn = blockIdx.x * 64;

    // stage W1[:, bn:bn+64] transposed -> Wt[n][k], bf16
    {
        int n = tid & 63;
        for (int k = tid >> 6; k < F0; k += 4) {
            Wt[n][k] = f2bf(W1[(size_t)k * D1 + bn + n]);
        }
    }
    __syncthreads();

    int w = tid >> 6;
    int lane = tid & 63;
    int l15 = lane & 15;
    int q = lane >> 4;
    int mr = bm + w * 16 + l15;
    if (mr > M - 1) mr = M - 1;   // clamp loads; stores predicated

    f32x4 acc0 = {0.f, 0.f, 0.f, 0.f};
    f32x4 acc1 = {0.f, 0.f, 0.f, 0.f};
    f32x4 acc2 = {0.f, 0.f, 0.f, 0.f};
    f32x4 acc3 = {0.f, 0.f, 0.f, 0.f};

#pragma unroll
    for (int k0 = 0; k0 < F0; k0 += 32) {
        const float* ap = x + (size_t)mr * F0 + k0 + q * 8;
        float4 a0 = *(const float4*)ap;
        float4 a1 = *(const float4*)(ap + 4);
        short8 af;
        af[0] = (short)f2bf(a0.x); af[1] = (short)f2bf(a0.y);
        af[2] = (short)f2bf(a0.z); af[3] = (short)f2bf(a0.w);
        af[4] = (short)f2bf(a1.x); af[5] = (short)f2bf(a1.y);
        af[6] = (short)f2bf(a1.z); af[7] = (short)f2bf(a1.w);

        short8 b0 = *(const short8*)&Wt[0 * 16 + l15][k0 + q * 8];
        short8 b1 = *(const short8*)&Wt[1 * 16 + l15][k0 + q * 8];
        short8 b2 = *(const short8*)&Wt[2 * 16 + l15][k0 + q * 8];
        short8 b3 = *(const short8*)&Wt[3 * 16 + l15][k0 + q * 8];

        acc0 = __builtin_amdgcn_mfma_f32_16x16x32_bf16(af, b0, acc0, 0, 0, 0);
        acc1 = __builtin_amdgcn_mfma_f32_16x16x32_bf16(af, b1, acc1, 0, 0, 0);
        acc2 = __builtin_amdgcn_mfma_f32_16x16x32_bf16(af, b2, acc2, 0, 0, 0);
        acc3 = __builtin_amdgcn_mfma_f32_16x16x32_bf16(af, b3, acc3, 0, 0, 0);
    }

    // epilogue: row = bm + w*16 + q*4 + reg, col = bn + nt*16 + l15
#pragma unroll
    for (int r = 0; r < 4; ++r) {
        int row = bm + w * 16 + q * 4 + r;
        if (row >= M) continue;
        size_t base = (size_t)row * D1 + bn;
        h1b[base + 0 * 16 + l15] = f2bf(acc0[r]);
        h1b[base + 1 * 16 + l15] = f2bf(acc1[r]);
        h1b[base + 2 * 16 + l15] = f2bf(acc2[r]);
        h1b[base + 3 * 16 + l15] = f2bf(acc3[r]);
    }
}

// ---------------- templated f32 GEMM, optional bf16 output ----------------

template<int BM, int BN, int BK, int TM, int TN, typename OT>
__global__ __launch_bounds__(256) void gemm_t(const float* __restrict__ A,
                                              const float* __restrict__ B,
                                              OT* __restrict__ C,
                                              int M, int N, int K) {
    constexpr int TX = BN / TN;
    constexpr int TY = BM / TM;
    static_assert(TX * TY == 256, "thread grid");
    constexpr int LDA = BM + 4;
    __shared__ float As[BK][LDA];
    __shared__ float Bs[BK][BN];

    int tid = threadIdx.x;
    int bm = blockIdx.y * BM;
    int bn = blockIdx.x * BN;
    int tx = tid % TX;
    int ty = tid / TX;

    float acc[TM][TN] = {};

    constexpr int AF4 = BM * BK / 4;
    constexpr int FPR = BK / 4;
    constexpr int BF4 = BK * BN / 4;
    constexpr int BPR = BN / 4;

    for (int k0 = 0; k0 < K; k0 += BK) {
#pragma unroll
        for (int f = tid; f < AF4; f += 256) {
            int r = f / FPR, c4 = f % FPR;
            int gr = bm + r; if (gr > M - 1) gr = M - 1;
            float4 v = *(const float4*)(A + (size_t)gr * K + k0 + c4 * 4);
            As[c4 * 4 + 0][r] = v.x;
            As[c4 * 4 + 1][r] = v.y;
            As[c4 * 4 + 2][r] = v.z;
            As[c4 * 4 + 3][r] = v.w;
        }
#pragma unroll
        for (int f = tid; f < BF4; f += 256) {
            int kk = f / BPR, j4 = f % BPR;
            *(float4*)&Bs[kk][j4 * 4] = *(const float4*)(B + (size_t)(k0 + kk) * N + bn + j4 * 4);
        }
        __syncthreads();
#pragma unroll
        for (int kk = 0; kk < BK; ++kk) {
            float a[TM], b[TN];
#pragma unroll
            for (int i = 0; i < TM; i += 4)
                *(float4*)&a[i] = *(const float4*)&As[kk][ty * TM + i];
            if constexpr (TN == 8) {
                *(float4*)&b[0] = *(const float4*)&Bs[kk][tx * 4];
                *(float4*)&b[4] = *(const float4*)&Bs[kk][BN / 2 + tx * 4];
            } else if constexpr (TN == 4) {
                *(float4*)&b[0] = *(const float4*)&Bs[kk][tx * 4];
            } else {
                b[0] = Bs[kk][tx * 2];
                b[1] = Bs[kk][tx * 2 + 1];
            }
#pragma unroll
            for (int i = 0; i < TM; ++i)
#pragma unroll
                for (int jj = 0; jj < TN; ++jj)
                    acc[i][jj] += a[i] * b[jj];
        }
        __syncthreads();
    }
#pragma unroll
    for (int i = 0; i < TM; ++i) {
        int gr = bm + ty * TM + i;
        if (gr >= M) break;
        if constexpr (sizeof(OT) == 2) {
            if constexpr (TN == 8) {
                uint2 p0, p1;
                p0.x = pack2bf(acc[i][0], acc[i][1]);
                p0.y = pack2bf(acc[i][2], acc[i][3]);
                p1.x = pack2bf(acc[i][4], acc[i][5]);
                p1.y = pack2bf(acc[i][6], acc[i][7]);
                *(uint2*)((u16*)C + (size_t)gr * N + bn + tx * 4) = p0;
                *(uint2*)((u16*)C + (size_t)gr * N + bn + BN / 2 + tx * 4) = p1;
            } else if constexpr (TN == 4) {
                uint2 p0;
                p0.x = pack2bf(acc[i][0], acc[i][1]);
                p0.y = pack2bf(acc[i][2], acc[i][3]);
                *(uint2*)((u16*)C + (size_t)gr * N + bn + tx * 4) = p0;
            } else {
                u32 p = pack2bf(acc[i][0], acc[i][1]);
                *(u32*)((u16*)C + (size_t)gr * N + bn + tx * 2) = p;
            }
        } else {
            if constexpr (TN == 8) {
                *(float4*)((float*)C + (size_t)gr * N + bn + tx * 4) = *(float4*)&acc[i][0];
                *(float4*)((float*)C + (size_t)gr * N + bn + BN / 2 + tx * 4) = *(float4*)&acc[i][4];
            } else if constexpr (TN == 4) {
                *(float4*)((float*)C + (size_t)gr * N + bn + tx * 4) = *(float4*)&acc[i][0];
            } else {
                *(float2*)((float*)C + (size_t)gr * N + bn + tx * 2) = *(float2*)&acc[i][0];
            }
        }
    }
}

// ---------------- per-node attention coefficients (bf16 h) ----------------

__global__ void alpha_bf16_kernel(const u16* __restrict__ h, const float* __restrict__ a_src,
                                  const float* __restrict__ a_dst, float* __restrict__ as,
                                  float* __restrict__ ad, int n, int H, int C) {
    int t = blockIdx.x * 256 + threadIdx.x;
    if (t >= n * H) return;
    int hh = t % H;
    const u16* hp    = h + (size_t)t * C;
    const float* asp = a_src + hh * C;
    const float* adp = a_dst + hh * C;
    float s1 = 0.f, s2 = 0.f;
    for (int c = 0; c < C; c += 4) {
        float4 hv = bf4_to_f4(*(const uint2*)(hp + c));
        float4 sv = *(const float4*)(asp + c);
        float4 dv = *(const float4*)(adp + c);
        s1 += hv.x * sv.x + hv.y * sv.y + hv.z * sv.z + hv.w * sv.w;
        s2 += hv.x * dv.x + hv.y * dv.y + hv.z * dv.z + hv.w * dv.w;
    }
    as[t] = s1;
    ad[t] = s2;
}

// ---------------- layer 1 aggregation: H=8, C=32, wave per node, bf16 h ----------------

__global__ __launch_bounds__(256) void agg1_kernel(const int* __restrict__ off, const int* __restrict__ csr,
                                                   const u16* __restrict__ h, const float* __restrict__ as,
                                                   const float* __restrict__ ad, const float* __restrict__ bias,
                                                   float* __restrict__ out) {
    int node = blockIdx.x * 4 + (threadIdx.x >> 6);
    if (node >= N_NODES) return;
    int lane = threadIdx.x & 63;
    int hh = lane >> 3;
    int j  = lane & 7;
    int s0 = off[node];
    int deg = off[node + 1] - s0;
    float adv = ad[node * H1 + hh];

    float4 acc = make_float4(0.f, 0.f, 0.f, 0.f);
    float dsum = 0.f;
    int i = 0;
    for (; i + 4 <= deg; i += 4) {
        int sa = csr[s0 + i];
        int sb = csr[s0 + i + 1];
        int sc = csr[s0 + i + 2];
        int sd = csr[s0 + i + 3];
        uint2 va = *(const uint2*)(h + (size_t)sa * D1 + hh * C1 + j * 4);
        uint2 vb = *(const uint2*)(h + (size_t)sb * D1 + hh * C1 + j * 4);
        uint2 vc = *(const uint2*)(h + (size_t)sc * D1 + hh * C1 + j * 4);
        uint2 vd = *(const uint2*)(h + (size_t)sd * D1 + hh * C1 + j * 4);
        float wa = __expf(lrelu(as[sa * H1 + hh] + adv));
        float wb = __expf(lrelu(as[sb * H1 + hh] + adv));
        float wc = __expf(lrelu(as[sc * H1 + hh] + adv));
        float wd = __expf(lrelu(as[sd * H1 + hh] + adv));
        float4 ha = bf4_to_f4(va);
        float4 hb = bf4_to_f4(vb);
        float4 hc = bf4_to_f4(vc);
        float4 hd = bf4_to_f4(vd);
        dsum += wa + wb + wc + wd;
        acc.x += wa * ha.x + wb * hb.x + wc * hc.x + wd * hd.x;
        acc.y += wa * ha.y + wb * hb.y + wc * hc.y + wd * hd.y;
        acc.z += wa * ha.z + wb * hb.z + wc * hc.z + wd * hd.z;
        acc.w += wa * ha.w + wb * hb.w + wc * hc.w + wd * hd.w;
    }
    for (; i < deg; ++i) {
        int s = csr[s0 + i];
        float4 hv = bf4_to_f4(*(const uint2*)(h + (size_t)s * D1 + hh * C1 + j * 4));
        float w = __expf(lrelu(as[s * H1 + hh] + adv));
        dsum += w;
        acc.x += w * hv.x; acc.y += w * hv.y; acc.z += w * hv.z; acc.w += w * hv.w;
    }
    float inv = 1.f / (dsum + 1e-16f);
    int ob = node * D1 + hh * C1 + j * 4;
    const float* bp = bias + hh * C1 + j * 4;
    float4 r;
    r.x = eluf(acc.x * inv + bp[0]);
    r.y = eluf(acc.y * inv + bp[1]);
    r.z = eluf(acc.z * inv + bp[2]);
    r.w = eluf(acc.w * inv + bp[3]);
    *(float4*)(out + ob) = r;
}

// ---------------- layer 2 aggregation: H=1, C=32, wave per node, bf16 h ----------------

__global__ __launch_bounds__(256) void agg32_kernel(const int* __restrict__ off, const int* __restrict__ csr,
                                                    const u16* __restrict__ h, const float* __restrict__ as,
                                                    const float* __restrict__ ad, const float* __restrict__ bias,
                                                    float* __restrict__ out) {
    int node = blockIdx.x * 4 + (threadIdx.x >> 6);
    if (node >= N_NODES) return;
    int lane = threadIdx.x & 63;
    int c = lane & 31;
    int half = lane >> 5;
    int s0 = off[node];
    int deg = off[node + 1] - s0;
    float adv = ad[node];

    float acc = 0.f, dsum = 0.f;
    int i = half;
    for (; i + 6 < deg; i += 8) {
        int sa = csr[s0 + i];
        int sb = csr[s0 + i + 2];
        int sc = csr[s0 + i + 4];
        int sd = csr[s0 + i + 6];
        float ha = bf2f(h[(size_t)sa * C2 + c]);
        float hb = bf2f(h[(size_t)sb * C2 + c]);
        float hc = bf2f(h[(size_t)sc * C2 + c]);
        float hd = bf2f(h[(size_t)sd * C2 + c]);
        float wa = __expf(lrelu(as[sa] + adv));
        float wb = __expf(lrelu(as[sb] + adv));
        float wc = __expf(lrelu(as[sc] + adv));
        float wd = __expf(lrelu(as[sd] + adv));
        dsum += wa + wb + wc + wd;
        acc += wa * ha + wb * hb + wc * hc + wd * hd;
    }
    for (; i < deg; i += 2) {
        int s = csr[s0 + i];
        float w = __expf(lrelu(as[s] + adv));
        dsum += w;
        acc += w * bf2f(h[(size_t)s * C2 + c]);
    }
    acc  += __shfl_xor(acc, 32);
    dsum += __shfl_xor(dsum, 32);
    if (half == 0) {
        out[(size_t)node * C2 + c] = eluf(acc / (dsum + 1e-16f) + bias[c]);
    }
}

// ---------------- layer 3 aggregation: H=1, C=64, wave per node, bf16 h, no ELU ----------------

__global__ __launch_bounds__(256) void agg64_kernel(const int* __restrict__ off, const int* __restrict__ csr,
                                                    const u16* __restrict__ h, const float* __restrict__ as,
                                                    const float* __restrict__ ad, const float* __restrict__ bias,
                                                    float* __restrict__ out) {
    int node = blockIdx.x * 4 + (threadIdx.x >> 6);
    if (node >= N_NODES) return;
    int lane = threadIdx.x & 63;
    int s0 = off[node];
    int deg = off[node + 1] - s0;
    float adv = ad[node];

    float acc = 0.f, dsum = 0.f;
    int i = 0;
    for (; i + 4 <= deg; i += 4) {
        int sa = csr[s0 + i];
        int sb = csr[s0 + i + 1];
        int sc = csr[s0 + i + 2];
        int sd = csr[s0 + i + 3];
        float ha = bf2f(h[(size_t)sa * C3 + lane]);
        float hb = bf2f(h[(size_t)sb * C3 + lane]);
        float hc = bf2f(h[(size_t)sc * C3 + lane]);
        float hd = bf2f(h[(size_t)sd * C3 + lane]);
        float wa = __expf(lrelu(as[sa] + adv));
        float wb = __expf(lrelu(as[sb] + adv));
        float wc = __expf(lrelu(as[sc] + adv));
        float wd = __expf(lrelu(as[sd] + adv));
        dsum += wa + wb + wc + wd;
        acc += wa * ha + wb * hb + wc * hc + wd * hd;
    }
    for (; i < deg; ++i) {
        int s = csr[s0 + i];
        float w = __expf(lrelu(as[s] + adv));
        dsum += w;
        acc += w * bf2f(h[(size_t)s * C3 + lane]);
    }
    out[(size_t)node * C3 + lane] = acc / (dsum + 1e-16f) + bias[lane];
}

// ---------------- launch ----------------

extern "C" void kernel_launch(void* const* d_in, const int* in_sizes, int n_in,
                              void* d_out, int out_size, void* d_ws, size_t ws_size,
                              hipStream_t stream) {
    const float* x   = (const float*)d_in[0];
    const int*   ei  = (const int*)d_in[1];
    const float* W1  = (const float*)d_in[2];
    const float* aS1 = (const float*)d_in[3];
    const float* aD1 = (const float*)d_in[4];
    const float* b1  = (const float*)d_in[5];
    const float* W2  = (const float*)d_in[6];
    const float* aS2 = (const float*)d_in[7];
    const float* aD2 = (const float*)d_in[8];
    const float* b2  = (const float*)d_in[9];
    const float* W3  = (const float*)d_in[10];
    const float* aS3 = (const float*)d_in[11];
    const float* aD3 = (const float*)d_in[12];
    const float* b3  = (const float*)d_in[13];
    float* out = (float*)d_out;

    char* p = (char*)d_ws;
    auto alloc = [&](size_t bytes) -> void* {
        void* r = (void*)p;
        p += (bytes + 255) & ~(size_t)255;
        return r;
    };
    u16*   h1b  = (u16*)alloc((size_t)N_NODES * D1 * 2);     // layer-1 features bf16
    float* bufB = (float*)alloc((size_t)N_NODES * D1 * 4);   // agg1 out f32 (x2)
    u16*   h2b  = (u16*)alloc((size_t)N_NODES * C2 * 2);     // layer-2 features bf16
    float* x3   = (float*)alloc((size_t)N_NODES * C2 * 4);   // agg2 out f32
    u16*   h3b  = (u16*)alloc((size_t)N_NODES * C3 * 2);     // layer-3 features bf16
    int*   deg  = (int*)alloc((size_t)N_NODES * 4);
    int*   off  = (int*)alloc((size_t)(N_NODES + 1) * 4);
    int*   cur  = (int*)alloc((size_t)N_NODES * 4);
    int*   csr  = (int*)alloc((size_t)ET * 4);
    float* asb  = (float*)alloc((size_t)N_NODES * H1 * 4);
    float* adb  = (float*)alloc((size_t)N_NODES * H1 * 4);
    int*   bsum = (int*)alloc((size_t)SCAN_NB * 4);
    int*   bbase= (int*)alloc((size_t)SCAN_NB * 4);

    const int* srcArr = ei;
    const int* dstArr = ei + N_EDGES;

    // --- CSR build ---
    hipMemsetAsync(deg, 0, (size_t)N_NODES * 4, stream);
    int eb = (ET + 255) / 256;
    hist_kernel<<<eb, 256, 0, stream>>>(dstArr, deg);
    partial_kernel<<<SCAN_NB, 256, 0, stream>>>(deg, bsum, N_NODES);
    bscan_kernel<<<1, 64, 0, stream>>>(bsum, bbase, off, N_NODES);
    finish_kernel<<<SCAN_NB, 256, 0, stream>>>(deg, bbase, off, cur, N_NODES);
    scatter_kernel<<<eb, 256, 0, stream>>>(srcArr, dstArr, cur, csr);

    int nb4 = (N_NODES + 3) / 4;

    // --- layer 1: MFMA gemm -> bf16 h1 ---
    gemm1_mfma<<<dim3(D1 / 64, (N_NODES + 63) / 64), 256, 0, stream>>>(x, W1, h1b, N_NODES);
    alpha_bf16_kernel<<<(N_NODES * H1 + 255) / 256, 256, 0, stream>>>(h1b, aS1, aD1, asb, adb, N_NODES, H1, C1);
    agg1_kernel<<<nb4, 256, 0, stream>>>(off, csr, h1b, asb, adb, b1, bufB);

    // --- layer 2: f32 gemm -> bf16 h2 ---
    gemm_t<64, 32, 32, 4, 2, u16><<<dim3(1, (N_NODES + 63) / 64), 256, 0, stream>>>(bufB, W2, h2b, N_NODES, C2, D1);
    alpha_bf16_kernel<<<(N_NODES + 255) / 256, 256, 0, stream>>>(h2b, aS2, aD2, asb, adb, N_NODES, 1, C2);
    agg32_kernel<<<nb4, 256, 0, stream>>>(off, csr, h2b, asb, adb, b2, x3);

    // --- layer 3: f32 gemm -> bf16 h3 ---
    gemm_t<64, 64, 32, 4, 4, u16><<<dim3(1, (N_NODES + 63) / 64), 256, 0, stream>>>(x3, W3, h3b, N_NODES, C3, C2);
    alpha_bf16_kernel<<<(N_NODES + 255) / 256, 256, 0, stream>>>(h3b, aS3, aD3, asb, adb, N_NODES, 1, C3);
    agg64_kernel<<<nb4, 256, 0, stream>>>(off, csr, h3b, asb, adb, b3, out);
}

// Round 10
// 393.507 us; speedup vs baseline: 1.7190x; 1.0431x over previous
//
#include <hip/hip_runtime.h>
#include <hip/hip_bf16.h>
#include <math.h>

#define N_NODES 50000
#define N_EDGES 800000
#define ET (N_EDGES + N_NODES)   // with self loops = 850000
#define F0 128
#define H1 8
#define C1 32
#define D1 (H1*C1)               // 256
#define C2 32
#define C3 64

#define SCAN_NB 64
#define SCAN_CH 4

typedef unsigned short u16;
typedef unsigned int u32;
typedef __attribute__((ext_vector_type(8))) short short8;
typedef __attribute__((ext_vector_type(4))) float f32x4;

__device__ __forceinline__ float lrelu(float x) { return x >= 0.f ? x : 0.2f * x; }
__device__ __forceinline__ float eluf(float x)  { return x > 0.f ? x : (expf(x) - 1.f); }

__device__ __forceinline__ u16 f2bf(float f) {
    u32 u = __float_as_uint(f);
    return (u16)((u + 0x7FFFu + ((u >> 16) & 1u)) >> 16);   // RNE
}
__device__ __forceinline__ u32 pack2bf(float lo, float hi) {
    return ((u32)f2bf(hi) << 16) | (u32)f2bf(lo);
}
__device__ __forceinline__ float bf2f(u16 v) {
    return __uint_as_float((u32)v << 16);
}
__device__ __forceinline__ float4 bf4_to_f4(uint2 v) {
    float4 r;
    r.x = __uint_as_float(v.x << 16);
    r.y = __uint_as_float(v.x & 0xFFFF0000u);
    r.z = __uint_as_float(v.y << 16);
    r.w = __uint_as_float(v.y & 0xFFFF0000u);
    return r;
}

// ---------------- CSR build ----------------

__global__ void hist_kernel(const int* __restrict__ dstArr, int* __restrict__ deg) {
    int e = blockIdx.x * 256 + threadIdx.x;
    if (e >= ET) return;
    int d = (e < N_EDGES) ? dstArr[e] : (e - N_EDGES);
    atomicAdd(&deg[d], 1);
}

__global__ __launch_bounds__(256) void partial_kernel(const int* __restrict__ deg,
                                                      int* __restrict__ bsum, int n) {
    __shared__ int sdata[256];
    int t = threadIdx.x;
    int base = (blockIdx.x * 256 + t) * SCAN_CH;
    int s = 0;
#pragma unroll
    for (int u = 0; u < SCAN_CH; ++u) {
        int ix = base + u;
        s += (ix < n) ? deg[ix] : 0;
    }
    sdata[t] = s;
    __syncthreads();
    for (int o = 128; o > 0; o >>= 1) {
        if (t < o) sdata[t] += sdata[t + o];
        __syncthreads();
    }
    if (t == 0) bsum[blockIdx.x] = sdata[0];
}

__global__ __launch_bounds__(64) void bscan_kernel(const int* __restrict__ bsum,
                                                   int* __restrict__ bbase,
                                                   int* __restrict__ off, int n) {
    int t = threadIdx.x;
    int v = (t < SCAN_NB) ? bsum[t] : 0;
    int orig = v;
#pragma unroll
    for (int o = 1; o < 64; o <<= 1) {
        int x = __shfl_up(v, o);
        if (t >= o) v += x;
    }
    if (t < SCAN_NB) bbase[t] = v - orig;
    if (t == 0) off[n] = ET;
}

__global__ __launch_bounds__(256) void finish_kernel(const int* __restrict__ deg,
                                                     const int* __restrict__ bbase,
                                                     int* __restrict__ off,
                                                     int* __restrict__ cur, int n) {
    __shared__ int sdata[256];
    int t = threadIdx.x;
    int base = (blockIdx.x * 256 + t) * SCAN_CH;
    int d[SCAN_CH];
    int s = 0;
#pragma unroll
    for (int u = 0; u < SCAN_CH; ++u) {
        int ix = base + u;
        d[u] = (ix < n) ? deg[ix] : 0;
        s += d[u];
    }
    sdata[t] = s;
    __syncthreads();
    for (int o = 1; o < 256; o <<= 1) {
        int x = (t >= o) ? sdata[t - o] : 0;
        __syncthreads();
        sdata[t] += x;
        __syncthreads();
    }
    int run = bbase[blockIdx.x] + sdata[t] - s;
#pragma unroll
    for (int u = 0; u < SCAN_CH; ++u) {
        int ix = base + u;
        if (ix < n) {
            off[ix] = run; cur[ix] = run;
            run += d[u];
        }
    }
}

__global__ void scatter_kernel(const int* __restrict__ srcArr, const int* __restrict__ dstArr,
                               int* __restrict__ cur, int* __restrict__ csr) {
    int e = blockIdx.x * 256 + threadIdx.x;
    if (e >= ET) return;
    int s, d;
    if (e < N_EDGES) { s = srcArr[e]; d = dstArr[e]; } else { s = d = e - N_EDGES; }
    int pos = atomicAdd(&cur[d], 1);
    csr[pos] = s;
}

// ---------------- gemm1: x[M,128](f32) @ W1[128,256] -> bf16, MFMA 16x16x32 ----------------
// Layouts (HW-verified): A[m=lane&15][k=(lane>>4)*8+j]; B[n=lane&15][k=...];
// C/D col=lane&15, row=(lane>>4)*4+reg.

#define WKS 136   // LDS k-stride in u16 (272 B, 16B multiple)

__global__ __launch_bounds__(256) void gemm1_mfma(const float* __restrict__ x,
                                                  const float* __restrict__ W1,
                                                  u16* __restrict__ h1b, int M) {
    __shared__ u16 Wt[64][WKS];
    int tid = threadIdx.x;
    int bm = blockIdx.y * 64;
    int bn = blockIdx.x * 64;

    {
        int n = tid & 63;
        for (int k = tid >> 6; k < F0; k += 4) {
            Wt[n][k] = f2bf(W1[(size_t)k * D1 + bn + n]);
        }
    }
    __syncthreads();

    int w = tid >> 6;
    int lane = tid & 63;
    int l15 = lane & 15;
    int q = lane >> 4;
    int mr = bm + w * 16 + l15;
    if (mr > M - 1) mr = M - 1;

    f32x4 acc0 = {0.f, 0.f, 0.f, 0.f};
    f32x4 acc1 = {0.f, 0.f, 0.f, 0.f};
    f32x4 acc2 = {0.f, 0.f, 0.f, 0.f};
    f32x4 acc3 = {0.f, 0.f, 0.f, 0.f};

#pragma unroll
    for (int k0 = 0; k0 < F0; k0 += 32) {
        const float* ap = x + (size_t)mr * F0 + k0 + q * 8;
        float4 a0 = *(const float4*)ap;
        float4 a1 = *(const float4*)(ap + 4);
        short8 af;
        af[0] = (short)f2bf(a0.x); af[1] = (short)f2bf(a0.y);
        af[2] = (short)f2bf(a0.z); af[3] = (short)f2bf(a0.w);
        af[4] = (short)f2bf(a1.x); af[5] = (short)f2bf(a1.y);
        af[6] = (short)f2bf(a1.z); af[7] = (short)f2bf(a1.w);

        short8 b0 = *(const short8*)&Wt[0 * 16 + l15][k0 + q * 8];
        short8 b1 = *(const short8*)&Wt[1 * 16 + l15][k0 + q * 8];
        short8 b2 = *(const short8*)&Wt[2 * 16 + l15][k0 + q * 8];
        short8 b3 = *(const short8*)&Wt[3 * 16 + l15][k0 + q * 8];

        acc0 = __builtin_amdgcn_mfma_f32_16x16x32_bf16(af, b0, acc0, 0, 0, 0);
        acc1 = __builtin_amdgcn_mfma_f32_16x16x32_bf16(af, b1, acc1, 0, 0, 0);
        acc2 = __builtin_amdgcn_mfma_f32_16x16x32_bf16(af, b2, acc2, 0, 0, 0);
        acc3 = __builtin_amdgcn_mfma_f32_16x16x32_bf16(af, b3, acc3, 0, 0, 0);
    }

#pragma unroll
    for (int r = 0; r < 4; ++r) {
        int row = bm + w * 16 + q * 4 + r;
        if (row >= M) continue;
        size_t base = (size_t)row * D1 + bn;
        h1b[base + 0 * 16 + l15] = f2bf(acc0[r]);
        h1b[base + 1 * 16 + l15] = f2bf(acc1[r]);
        h1b[base + 2 * 16 + l15] = f2bf(acc2[r]);
        h1b[base + 3 * 16 + l15] = f2bf(acc3[r]);
    }
}

// ---------------- gemm2: x2[M,256](bf16) @ W2[256,32] -> bf16, MFMA ----------------

#define WK2S 264   // 528 B rows, 16B multiple

__global__ __launch_bounds__(256) void gemm2_mfma(const u16* __restrict__ A,
                                                  const float* __restrict__ W2,
                                                  u16* __restrict__ h2b, int M) {
    __shared__ u16 Wt[32][WK2S];
    int tid = threadIdx.x;
    int bm = blockIdx.y * 64;
    for (int idx = tid; idx < 32 * D1; idx += 256) {
        int n = idx & 31, k = idx >> 5;
        Wt[n][k] = f2bf(W2[(size_t)k * C2 + n]);
    }
    __syncthreads();

    int w = tid >> 6, lane = tid & 63, l15 = lane & 15, q = lane >> 4;
    int mr = bm + w * 16 + l15;
    if (mr > M - 1) mr = M - 1;

    f32x4 acc0 = {0.f, 0.f, 0.f, 0.f};
    f32x4 acc1 = {0.f, 0.f, 0.f, 0.f};
#pragma unroll
    for (int k0 = 0; k0 < D1; k0 += 32) {
        short8 af = *(const short8*)(A + (size_t)mr * D1 + k0 + q * 8);
        short8 b0 = *(const short8*)&Wt[0 * 16 + l15][k0 + q * 8];
        short8 b1 = *(const short8*)&Wt[1 * 16 + l15][k0 + q * 8];
        acc0 = __builtin_amdgcn_mfma_f32_16x16x32_bf16(af, b0, acc0, 0, 0, 0);
        acc1 = __builtin_amdgcn_mfma_f32_16x16x32_bf16(af, b1, acc1, 0, 0, 0);
    }
#pragma unroll
    for (int r = 0; r < 4; ++r) {
        int row = bm + w * 16 + q * 4 + r;
        if (row >= M) continue;
        h2b[(size_t)row * C2 + 0 * 16 + l15] = f2bf(acc0[r]);
        h2b[(size_t)row * C2 + 1 * 16 + l15] = f2bf(acc1[r]);
    }
}

// ---------------- gemm3: x3[M,32](bf16) @ W3[32,64] -> bf16, MFMA, single k-step ----------------

#define WK3S 40   // 80 B rows, 16B multiple

__global__ __launch_bounds__(256) void gemm3_mfma(const u16* __restrict__ A,
                                                  const float* __restrict__ W3,
                                                  u16* __restrict__ h3b, int M) {
    __shared__ u16 Wt[64][WK3S];
    int tid = threadIdx.x;
    int bm = blockIdx.y * 64;
    for (int idx = tid; idx < 64 * C2; idx += 256) {
        int n = idx & 63, k = idx >> 6;
        Wt[n][k] = f2bf(W3[(size_t)k * C3 + n]);
    }
    __syncthreads();

    int w = tid >> 6, lane = tid & 63, l15 = lane & 15, q = lane >> 4;
    int mr = bm + w * 16 + l15;
    if (mr > M - 1) mr = M - 1;

    short8 af = *(const short8*)(A + (size_t)mr * C2 + q * 8);
    short8 b0 = *(const short8*)&Wt[0 * 16 + l15][q * 8];
    short8 b1 = *(const short8*)&Wt[1 * 16 + l15][q * 8];
    short8 b2 = *(const short8*)&Wt[2 * 16 + l15][q * 8];
    short8 b3 = *(const short8*)&Wt[3 * 16 + l15][q * 8];

    f32x4 acc0 = {0.f, 0.f, 0.f, 0.f};
    f32x4 acc1 = {0.f, 0.f, 0.f, 0.f};
    f32x4 acc2 = {0.f, 0.f, 0.f, 0.f};
    f32x4 acc3 = {0.f, 0.f, 0.f, 0.f};
    acc0 = __builtin_amdgcn_mfma_f32_16x16x32_bf16(af, b0, acc0, 0, 0, 0);
    acc1 = __builtin_amdgcn_mfma_f32_16x16x32_bf16(af, b1, acc1, 0, 0, 0);
    acc2 = __builtin_amdgcn_mfma_f32_16x16x32_bf16(af, b2, acc2, 0, 0, 0);
    acc3 = __builtin_amdgcn_mfma_f32_16x16x32_bf16(af, b3, acc3, 0, 0, 0);

#pragma unroll
    for (int r = 0; r < 4; ++r) {
        int row = bm + w * 16 + q * 4 + r;
        if (row >= M) continue;
        size_t base = (size_t)row * C3;
        h3b[base + 0 * 16 + l15] = f2bf(acc0[r]);
        h3b[base + 1 * 16 + l15] = f2bf(acc1[r]);
        h3b[base + 2 * 16 + l15] = f2bf(acc2[r]);
        h3b[base + 3 * 16 + l15] = f2bf(acc3[r]);
    }
}

// ---------------- per-node attention coefficients (bf16 h) ----------------

__global__ void alpha_bf16_kernel(const u16* __restrict__ h, const float* __restrict__ a_src,
                                  const float* __restrict__ a_dst, float* __restrict__ as,
                                  float* __restrict__ ad, int n, int H, int C) {
    int t = blockIdx.x * 256 + threadIdx.x;
    if (t >= n * H) return;
    int hh = t % H;
    const u16* hp    = h + (size_t)t * C;
    const float* asp = a_src + hh * C;
    const float* adp = a_dst + hh * C;
    float s1 = 0.f, s2 = 0.f;
    for (int c = 0; c < C; c += 4) {
        float4 hv = bf4_to_f4(*(const uint2*)(hp + c));
        float4 sv = *(const float4*)(asp + c);
        float4 dv = *(const float4*)(adp + c);
        s1 += hv.x * sv.x + hv.y * sv.y + hv.z * sv.z + hv.w * sv.w;
        s2 += hv.x * dv.x + hv.y * dv.y + hv.z * dv.z + hv.w * dv.w;
    }
    as[t] = s1;
    ad[t] = s2;
}

// ---------------- layer 1 aggregation: H=8, C=32, wave per node, bf16 in/out ----------------

__global__ __launch_bounds__(256) void agg1_kernel(const int* __restrict__ off, const int* __restrict__ csr,
                                                   const u16* __restrict__ h, const float* __restrict__ as,
                                                   const float* __restrict__ ad, const float* __restrict__ bias,
                                                   u16* __restrict__ outb) {
    int node = blockIdx.x * 4 + (threadIdx.x >> 6);
    if (node >= N_NODES) return;
    int lane = threadIdx.x & 63;
    int hh = lane >> 3;
    int j  = lane & 7;
    int s0 = off[node];
    int deg = off[node + 1] - s0;
    float adv = ad[node * H1 + hh];

    float4 acc = make_float4(0.f, 0.f, 0.f, 0.f);
    float dsum = 0.f;
    int i = 0;
    for (; i + 4 <= deg; i += 4) {
        int sa = csr[s0 + i];
        int sb = csr[s0 + i + 1];
        int sc = csr[s0 + i + 2];
        int sd = csr[s0 + i + 3];
        uint2 va = *(const uint2*)(h + (size_t)sa * D1 + hh * C1 + j * 4);
        uint2 vb = *(const uint2*)(h + (size_t)sb * D1 + hh * C1 + j * 4);
        uint2 vc = *(const uint2*)(h + (size_t)sc * D1 + hh * C1 + j * 4);
        uint2 vd = *(const uint2*)(h + (size_t)sd * D1 + hh * C1 + j * 4);
        float wa = __expf(lrelu(as[sa * H1 + hh] + adv));
        float wb = __expf(lrelu(as[sb * H1 + hh] + adv));
        float wc = __expf(lrelu(as[sc * H1 + hh] + adv));
        float wd = __expf(lrelu(as[sd * H1 + hh] + adv));
        float4 ha = bf4_to_f4(va);
        float4 hb = bf4_to_f4(vb);
        float4 hc = bf4_to_f4(vc);
        float4 hd = bf4_to_f4(vd);
        dsum += wa + wb + wc + wd;
        acc.x += wa * ha.x + wb * hb.x + wc * hc.x + wd * hd.x;
        acc.y += wa * ha.y + wb * hb.y + wc * hc.y + wd * hd.y;
        acc.z += wa * ha.z + wb * hb.z + wc * hc.z + wd * hd.z;
        acc.w += wa * ha.w + wb * hb.w + wc * hc.w + wd * hd.w;
    }
    for (; i < deg; ++i) {
        int s = csr[s0 + i];
        float4 hv = bf4_to_f4(*(const uint2*)(h + (size_t)s * D1 + hh * C1 + j * 4));
        float w = __expf(lrelu(as[s * H1 + hh] + adv));
        dsum += w;
        acc.x += w * hv.x; acc.y += w * hv.y; acc.z += w * hv.z; acc.w += w * hv.w;
    }
    float inv = 1.f / (dsum + 1e-16f);
    int ob = node * D1 + hh * C1 + j * 4;
    const float* bp = bias + hh * C1 + j * 4;
    float rx = eluf(acc.x * inv + bp[0]);
    float ry = eluf(acc.y * inv + bp[1]);
    float rz = eluf(acc.z * inv + bp[2]);
    float rw = eluf(acc.w * inv + bp[3]);
    uint2 pr;
    pr.x = pack2bf(rx, ry);
    pr.y = pack2bf(rz, rw);
    *(uint2*)(outb + ob) = pr;
}

// ---------------- layer 2 aggregation: H=1, C=32, wave per node, bf16 in/out ----------------

__global__ __launch_bounds__(256) void agg32_kernel(const int* __restrict__ off, const int* __restrict__ csr,
                                                    const u16* __restrict__ h, const float* __restrict__ as,
                                                    const float* __restrict__ ad, const float* __restrict__ bias,
                                                    u16* __restrict__ outb) {
    int node = blockIdx.x * 4 + (threadIdx.x >> 6);
    if (node >= N_NODES) return;
    int lane = threadIdx.x & 63;
    int c = lane & 31;
    int half = lane >> 5;
    int s0 = off[node];
    int deg = off[node + 1] - s0;
    float adv = ad[node];

    float acc = 0.f, dsum = 0.f;
    int i = half;
    for (; i + 6 < deg; i += 8) {
        int sa = csr[s0 + i];
        int sb = csr[s0 + i + 2];
        int sc = csr[s0 + i + 4];
        int sd = csr[s0 + i + 6];
        float ha = bf2f(h[(size_t)sa * C2 + c]);
        float hb = bf2f(h[(size_t)sb * C2 + c]);
        float hc = bf2f(h[(size_t)sc * C2 + c]);
        float hd = bf2f(h[(size_t)sd * C2 + c]);
        float wa = __expf(lrelu(as[sa] + adv));
        float wb = __expf(lrelu(as[sb] + adv));
        float wc = __expf(lrelu(as[sc] + adv));
        float wd = __expf(lrelu(as[sd] + adv));
        dsum += wa + wb + wc + wd;
        acc += wa * ha + wb * hb + wc * hc + wd * hd;
    }
    for (; i < deg; i += 2) {
        int s = csr[s0 + i];
        float w = __expf(lrelu(as[s] + adv));
        dsum += w;
        acc += w * bf2f(h[(size_t)s * C2 + c]);
    }
    acc  += __shfl_xor(acc, 32);
    dsum += __shfl_xor(dsum, 32);
    if (half == 0) {
        outb[(size_t)node * C2 + c] = f2bf(eluf(acc / (dsum + 1e-16f) + bias[c]));
    }
}

// ---------------- layer 3 aggregation: H=1, C=64, wave per node, bf16 h, f32 out, no ELU ----------------

__global__ __launch_bounds__(256) void agg64_kernel(const int* __restrict__ off, const int* __restrict__ csr,
                                                    const u16* __restrict__ h, const float* __restrict__ as,
                                                    const float* __restrict__ ad, const float* __restrict__ bias,
                                                    float* __restrict__ out) {
    int node = blockIdx.x * 4 + (threadIdx.x >> 6);
    if (node >= N_NODES) return;
    int lane = threadIdx.x & 63;
    int s0 = off[node];
    int deg = off[node + 1] - s0;
    float adv = ad[node];

    float acc = 0.f, dsum = 0.f;
    int i = 0;
    for (; i + 4 <= deg; i += 4) {
        int sa = csr[s0 + i];
        int sb = csr[s0 + i + 1];
        int sc = csr[s0 + i + 2];
        int sd = csr[s0 + i + 3];
        float ha = bf2f(h[(size_t)sa * C3 + lane]);
        float hb = bf2f(h[(size_t)sb * C3 + lane]);
        float hc = bf2f(h[(size_t)sc * C3 + lane]);
        float hd = bf2f(h[(size_t)sd * C3 + lane]);
        float wa = __expf(lrelu(as[sa] + adv));
        float wb = __expf(lrelu(as[sb] + adv));
        float wc = __expf(lrelu(as[sc] + adv));
        float wd = __expf(lrelu(as[sd] + adv));
        dsum += wa + wb + wc + wd;
        acc += wa * ha + wb * hb + wc * hc + wd * hd;
    }
    for (; i < deg; ++i) {
        int s = csr[s0 + i];
        float w = __expf(lrelu(as[s] + adv));
        dsum += w;
        acc += w * bf2f(h[(size_t)s * C3 + lane]);
    }
    out[(size_t)node * C3 + lane] = acc / (dsum + 1e-16f) + bias[lane];
}

// ---------------- launch ----------------

extern "C" void kernel_launch(void* const* d_in, const int* in_sizes, int n_in,
                              void* d_out, int out_size, void* d_ws, size_t ws_size,
                              hipStream_t stream) {
    const float* x   = (const float*)d_in[0];
    const int*   ei  = (const int*)d_in[1];
    const float* W1  = (const float*)d_in[2];
    const float* aS1 = (const float*)d_in[3];
    const float* aD1 = (const float*)d_in[4];
    const float* b1  = (const float*)d_in[5];
    const float* W2  = (const float*)d_in[6];
    const float* aS2 = (const float*)d_in[7];
    const float* aD2 = (const float*)d_in[8];
    const float* b2  = (const float*)d_in[9];
    const float* W3  = (const float*)d_in[10];
    const float* aS3 = (const float*)d_in[11];
    const float* aD3 = (const float*)d_in[12];
    const float* b3  = (const float*)d_in[13];
    float* out = (float*)d_out;

    char* p = (char*)d_ws;
    auto alloc = [&](size_t bytes) -> void* {
        void* r = (void*)p;
        p += (bytes + 255) & ~(size_t)255;
        return r;
    };
    u16*   h1b  = (u16*)alloc((size_t)N_NODES * D1 * 2);   // layer-1 features bf16
    u16*   x2b  = (u16*)alloc((size_t)N_NODES * D1 * 2);   // agg1 out bf16
    u16*   h2b  = (u16*)alloc((size_t)N_NODES * C2 * 2);   // layer-2 features bf16
    u16*   x3b  = (u16*)alloc((size_t)N_NODES * C2 * 2);   // agg2 out bf16
    u16*   h3b  = (u16*)alloc((size_t)N_NODES * C3 * 2);   // layer-3 features bf16
    int*   deg  = (int*)alloc((size_t)N_NODES * 4);
    int*   off  = (int*)alloc((size_t)(N_NODES + 1) * 4);
    int*   cur  = (int*)alloc((size_t)N_NODES * 4);
    int*   csr  = (int*)alloc((size_t)ET * 4);
    float* asb  = (float*)alloc((size_t)N_NODES * H1 * 4);
    float* adb  = (float*)alloc((size_t)N_NODES * H1 * 4);
    int*   bsum = (int*)alloc((size_t)SCAN_NB * 4);
    int*   bbase= (int*)alloc((size_t)SCAN_NB * 4);

    const int* srcArr = ei;
    const int* dstArr = ei + N_EDGES;

    // --- CSR build ---
    hipMemsetAsync(deg, 0, (size_t)N_NODES * 4, stream);
    int eb = (ET + 255) / 256;
    hist_kernel<<<eb, 256, 0, stream>>>(dstArr, deg);
    partial_kernel<<<SCAN_NB, 256, 0, stream>>>(deg, bsum, N_NODES);
    bscan_kernel<<<1, 64, 0, stream>>>(bsum, bbase, off, N_NODES);
    finish_kernel<<<SCAN_NB, 256, 0, stream>>>(deg, bbase, off, cur, N_NODES);
    scatter_kernel<<<eb, 256, 0, stream>>>(srcArr, dstArr, cur, csr);

    int nb4 = (N_NODES + 3) / 4;
    int mb64 = (N_NODES + 63) / 64;

    // --- layer 1 ---
    gemm1_mfma<<<dim3(D1 / 64, mb64), 256, 0, stream>>>(x, W1, h1b, N_NODES);
    alpha_bf16_kernel<<<(N_NODES * H1 + 255) / 256, 256, 0, stream>>>(h1b, aS1, aD1, asb, adb, N_NODES, H1, C1);
    agg1_kernel<<<nb4, 256, 0, stream>>>(off, csr, h1b, asb, adb, b1, x2b);

    // --- layer 2 ---
    gemm2_mfma<<<dim3(1, mb64), 256, 0, stream>>>(x2b, W2, h2b, N_NODES);
    alpha_bf16_kernel<<<(N_NODES + 255) / 256, 256, 0, stream>>>(h2b, aS2, aD2, asb, adb, N_NODES, 1, C2);
    agg32_kernel<<<nb4, 256, 0, stream>>>(off, csr, h2b, asb, adb, b2, x3b);

    // --- layer 3 ---
    gemm3_mfma<<<dim3(1, mb64), 256, 0, stream>>>(x3b, W3, h3b, N_NODES);
    alpha_bf16_kernel<<<(N_NODES + 255) / 256, 256, 0, stream>>>(h3b, aS3, aD3, asb, adb, N_NODES, 1, C3);
    agg64_kernel<<<nb4, 256, 0, stream>>>(off, csr, h3b, asb, adb, b3, out);
}